// Round 13
// baseline (269.512 us; speedup 1.0000x reference)
//
#include <hip/hip_runtime.h>
#include <hip/hip_bf16.h>

#define SEQ 4096
#define BSZ 2
#define NH 8
#define HD 64
#define DMODEL 512

typedef __bf16 bf16_t;
typedef __bf16 bf16x8 __attribute__((ext_vector_type(8)));
typedef __bf16 bf16x4 __attribute__((ext_vector_type(4)));
typedef float f32x4 __attribute__((ext_vector_type(4)));

__device__ __forceinline__ f32x4 mfma16(bf16x8 a, bf16x8 b, f32x4 c) {
    return __builtin_amdgcn_mfma_f32_16x16x32_bf16(a, b, c, 0, 0, 0);
}

__device__ __forceinline__ bf16x8 ld8(const bf16_t* p) {
    return *reinterpret_cast<const bf16x8*>(p);
}

__device__ __forceinline__ uint32_t pack2(bf16_t a, bf16_t b) {
    union { bf16_t h[2]; uint32_t u; } x;
    x.h[0] = a; x.h[1] = b;
    return x.u;
}

// async global->LDS DMA, 16 B/lane; data lands at lds base + lane*16
__device__ __forceinline__ void gl_lds16(const bf16_t* g, bf16_t* l) {
    __builtin_amdgcn_global_load_lds(
        (const __attribute__((address_space(1))) uint32_t*)g,
        (__attribute__((address_space(3))) uint32_t*)l,
        16, 0, 0);
}

// ---------------- fused cast fp32 -> bf16 (x + all 4 weights) ----------------
__global__ void cast_all(const float* __restrict__ x,
                         const float* __restrict__ wq, const float* __restrict__ wk,
                         const float* __restrict__ wv, const float* __restrict__ wo,
                         bf16_t* __restrict__ Xb, bf16_t* __restrict__ Wc,
                         bf16_t* __restrict__ Wob) {
    int i = blockIdx.x * blockDim.x + threadIdx.x;
    const float* src;
    bf16_t* dst;
    int j;
    if (i < 1048576) { src = x; dst = Xb; j = i; }
    else {
        int k = i - 1048576;
        int w = k >> 16;
        j = k & 65535;
        src = (w == 0) ? wq : (w == 1) ? wk : (w == 2) ? wv : wo;
        dst = (w == 3) ? Wob : Wc + w * 262144;
    }
    float4 v = reinterpret_cast<const float4*>(src)[j];
    bf16x4 o;
    o[0] = (bf16_t)v.x; o[1] = (bf16_t)v.y; o[2] = (bf16_t)v.z; o[3] = (bf16_t)v.w;
    reinterpret_cast<bf16x4*>(dst)[j] = o;
}

// ---------------- m97-style GEMM core (128x128) ----------------
__device__ __forceinline__ void gemm_core_128(const bf16_t* __restrict__ A,
                                              const bf16_t* __restrict__ B,
                                              int m0, int n0,
                                              bf16_t* As, bf16_t* Bs,
                                              f32x4 acc[4][4]) {
    const int t = threadIdx.x;
    const int lane = t & 63;
    const int wid = t >> 6;
    const int c = lane & 15, quad = lane >> 4;
    const int wm = wid & 1, wn = wid >> 1;

#pragma unroll
    for (int i = 0; i < 4; i++)
#pragma unroll
        for (int j = 0; j < 4; j++) acc[i][j] = f32x4{0.f, 0.f, 0.f, 0.f};

    const int lrow = lane >> 2;
    const int lch = lane & 3;
    const bf16_t* Ag = A + (size_t)(m0 + wid * 32 + lrow) * 512 + lch * 8;
    const bf16_t* Bg = B + (size_t)(n0 + wid * 32 + lrow) * 512 + lch * 8;
    bf16_t* Asw0 = As + (wid * 32) * 32;
    bf16_t* Asw1 = As + (wid * 32 + 16) * 32;
    bf16_t* Bsw0 = Bs + (wid * 32) * 32;
    bf16_t* Bsw1 = Bs + (wid * 32 + 16) * 32;

    for (int k0 = 0; k0 < 512; k0 += 32) {
        gl_lds16(Ag + k0, Asw0);
        gl_lds16(Ag + 16 * 512 + k0, Asw1);
        gl_lds16(Bg + k0, Bsw0);
        gl_lds16(Bg + 16 * 512 + k0, Bsw1);
        __syncthreads();

        bf16x8 a[4], b[4];
#pragma unroll
        for (int i = 0; i < 4; i++) a[i] = ld8(&As[(wm * 64 + i * 16 + c) * 32 + quad * 8]);
#pragma unroll
        for (int j = 0; j < 4; j++) b[j] = ld8(&Bs[(wn * 64 + j * 16 + c) * 32 + quad * 8]);
#pragma unroll
        for (int i = 0; i < 4; i++)
#pragma unroll
            for (int j = 0; j < 4; j++) acc[i][j] = mfma16(a[i], b[j], acc[i][j]);

        __syncthreads();
    }
}

// ---------------- GEMM1 + fused RoPE epilogue ----------------
__global__ __launch_bounds__(256) void gemm_qkv(const bf16_t* __restrict__ A,
                                                const bf16_t* __restrict__ W,
                                                bf16_t* __restrict__ Qb,
                                                bf16_t* __restrict__ Kb,
                                                bf16_t* __restrict__ Vb,
                                                const int* __restrict__ Vpar) {
    __shared__ bf16_t As[128 * 32];
    __shared__ bf16_t Bs[128 * 32];
    const int lane = threadIdx.x & 63;
    const int wid = threadIdx.x >> 6;
    const int c = lane & 15, quad = lane >> 4;
    const int wm = wid & 1, wn = wid >> 1;
    const int m0 = blockIdx.x * 128;
    const int n0 = blockIdx.y * 128;

    f32x4 acc[4][4];
    gemm_core_128(A, W, m0, n0, As, Bs, acc);

    const int Vv = Vpar[0];
    const float qs = 0.1803368801111204f;   // 0.125 * log2(e)

#pragma unroll
    for (int i = 0; i < 4; i++) {
        int mbase = m0 + wm * 64 + i * 16 + quad * 4;
#pragma unroll
        for (int j = 0; j < 4; j++) {
            int col = n0 + wn * 64 + j * 16 + c;
            int which = col >> 9;            // uniform per (wave, j)
            int h = (col >> 6) & 7;
            int d = col & 63;
            f32x4 v = acc[i][j];
            if (which < 2) {                 // rope Q / K (wave-uniform branch)
                int fidx = (d & 31) >> 1;
                float inv = exp2f((float)fidx * -0.8304820237218407f);
                bool hi = (d >= 32);
                bool odd = (d & 1);
                f32x4 part;
#pragma unroll
                for (int r = 0; r < 4; r++) part[r] = __shfl_xor(v[r], 1, 64);
#pragma unroll
                for (int r = 0; r < 4; r++) {
                    int s = (mbase + r) & 4095;
                    int tq = s / Vv;
                    int vq = s - tq * Vv;
                    float ang = (float)(hi ? vq : tq) * inv;
                    float sn = __sinf(ang), cs = __cosf(ang);
                    float xe = odd ? part[r] : v[r];
                    float xo = odd ? v[r] : part[r];
                    v[r] = odd ? (xe * sn + xo * cs) : (xe * cs - xo * sn);
                }
                if (which == 0) {
#pragma unroll
                    for (int r = 0; r < 4; r++) v[r] *= qs;
                }
            }
            bf16_t* dst = (which == 0) ? Qb : ((which == 1) ? Kb : Vb);
#pragma unroll
            for (int r = 0; r < 4; r++) {
                int m = mbase + r;
                int b_ = m >> 12;
                int s = m & 4095;
                dst[((size_t)(b_ * NH + h) * SEQ + s) * HD + d] = (bf16_t)v[r];
            }
        }
    }
}

// ---------------- GEMM2: 128x64 tiles, grid (64,8) ----------------
__global__ __launch_bounds__(256) void gemm_out(const bf16_t* __restrict__ A,
                                                const bf16_t* __restrict__ W,
                                                float* __restrict__ out) {
    __shared__ bf16_t As[128 * 32];
    __shared__ bf16_t Bs[64 * 32];
    const int t = threadIdx.x;
    const int lane = t & 63;
    const int wid = t >> 6;
    const int c = lane & 15, quad = lane >> 4;
    const int m0 = blockIdx.x * 128;
    const int n0 = blockIdx.y * 64;

    f32x4 acc[2][4];
#pragma unroll
    for (int i = 0; i < 2; i++)
#pragma unroll
        for (int j = 0; j < 4; j++) acc[i][j] = f32x4{0.f, 0.f, 0.f, 0.f};

    const int lrow = lane >> 2;
    const int lch = lane & 3;
    const bf16_t* Ag = A + (size_t)(m0 + wid * 32 + lrow) * 512 + lch * 8;
    const bf16_t* Bg = W + (size_t)(n0 + wid * 16 + lrow) * 512 + lch * 8;
    bf16_t* Asw0 = As + (wid * 32) * 32;
    bf16_t* Asw1 = As + (wid * 32 + 16) * 32;
    bf16_t* Bsw = Bs + (wid * 16) * 32;

    for (int k0 = 0; k0 < 512; k0 += 32) {
        gl_lds16(Ag + k0, Asw0);
        gl_lds16(Ag + 16 * 512 + k0, Asw1);
        gl_lds16(Bg + k0, Bsw);
        __syncthreads();

        bf16x8 a[2], b[4];
#pragma unroll
        for (int i = 0; i < 2; i++) a[i] = ld8(&As[(wid * 32 + i * 16 + c) * 32 + quad * 8]);
#pragma unroll
        for (int j = 0; j < 4; j++) b[j] = ld8(&Bs[(j * 16 + c) * 32 + quad * 8]);
#pragma unroll
        for (int i = 0; i < 2; i++)
#pragma unroll
            for (int j = 0; j < 4; j++) acc[i][j] = mfma16(a[i], b[j], acc[i][j]);

        __syncthreads();
    }

#pragma unroll
    for (int i = 0; i < 2; i++) {
        int mbase = m0 + wid * 32 + i * 16 + quad * 4;
#pragma unroll
        for (int j = 0; j < 4; j++) {
            int col = n0 + j * 16 + c;
#pragma unroll
            for (int r = 0; r < 4; r++)
                out[(size_t)(mbase + r) * DMODEL + col] = acc[i][j][r];
        }
    }
}

// ---------------- Flash attention v13: r12 + intra-iteration phase interleave ----------------
// Identical staging/structure to r12 (K via swizzled-source DMA, V reg-
// prefetch + transposed ds_write, double-buffered, 1 barrier/iter).
// Compute section reordered so VALU (exp2/pack) blocks sit between
// independent MFMA blocks: S(n=0..2) -> softmax-a(n=0,1) -> S(n=3) ->
// PV(ks=0) -> softmax-b(n=2,3) -> PV(ks=1). Lets one wave keep both the
// matrix and vector pipes busy (r12 counters showed the phases serialized:
// MfmaUtil+VALUBusy+LDS ~= 95% of wall with 2 waves/SIMD in barrier
// lockstep).
__global__ __launch_bounds__(256, 2) void flash_attn(const bf16_t* __restrict__ Q,
                                                     const bf16_t* __restrict__ K,
                                                     const bf16_t* __restrict__ V,
                                                     bf16_t* __restrict__ Y) {
    // per pair 32768 B: K buf0 8K | K buf1 8K | V^T buf0 8K | V^T buf1 8K
    __shared__ __align__(16) unsigned char smem[65536];

    const int t = threadIdx.x;
    const int lane = t & 63;
    const int c = lane & 15, quad = lane >> 4;
    const int wid = t >> 6;            // 0..3
    const int w = wid & 1;             // q-wave id == K-stage half id
    const int pr = wid >> 1;           // kv pair 0/1
    const int bh = blockIdx.y;
    const int qw = blockIdx.x * 128 + w * 64;

    size_t base = (size_t)bh * SEQ * HD;
    const bf16_t* Qp = Q + base;
    const bf16_t* Vp = V + base + (size_t)pr * 2048 * HD;

    unsigned char* pairBase = smem + pr * 32768;

    // K DMA swizzled source pointers: wave w stages tile rows [w*32, w*32+32)
    const bf16_t* Kpb = K + base + (size_t)pr * 2048 * HD;
    int srcOff = w * 4096 + ((lane >> 3) * 128) +
                 (((lane & 7) ^ ((lane >> 3) & 3)) * 16);
    const bf16_t* kE = (const bf16_t*)((const unsigned char*)Kpb + srcOff);
    const bf16_t* kO = (const bf16_t*)((const unsigned char*)Kpb + (srcOff ^ 64));

    bf16x8 qf[4][2];
#pragma unroll
    for (int qt = 0; qt < 4; qt++)
#pragma unroll
        for (int ks = 0; ks < 2; ks++)
            qf[qt][ks] = ld8(Qp + (size_t)(qw + qt * 16 + c) * HD + ks * 32 + quad * 8);

    f32x4 acc[4][4];
#pragma unroll
    for (int qt = 0; qt < 4; qt++)
#pragma unroll
        for (int dt = 0; dt < 4; dt++) acc[qt][dt] = f32x4{0.f, 0.f, 0.f, 0.f};
    float lsum[4] = {0.f, 0.f, 0.f, 0.f};

    // V staging (pair's 128 threads): rows kva,kva+1, d in [dc, dc+16)
    const int tp = t & 127;
    const int kva = 2 * (tp & 31);
    const int dc = 16 * (tp >> 5);

    // pre-loop: K tile 0 DMA into buf0; V tile 0 into regs
    {
        bf16_t* dst = (bf16_t*)(pairBase + w * 4096);
#pragma unroll
        for (int i = 0; i < 4; i++)
            gl_lds16(((i & 1) ? kO : kE) + i * 512, dst + i * 512);
        kE += 4096; kO += 4096;
    }
    bf16x8 vr0 = ld8(Vp + (size_t)kva * HD + dc);
    bf16x8 vr1 = ld8(Vp + (size_t)(kva + 1) * HD + dc);
    bf16x8 vr2 = ld8(Vp + (size_t)kva * HD + dc + 8);
    bf16x8 vr3 = ld8(Vp + (size_t)(kva + 1) * HD + dc + 8);

    for (int kt = 0; kt < 32; kt++) {
        uint32_t* vt = (uint32_t*)(pairBase + 16384 + (kt & 1) * 8192);

        // V transpose+swizzle stage for tile kt
#pragma unroll
        for (int j = 0; j < 8; j++) {
            int d0 = dc + j;
            int sv0 = (d0 & 7) ^ ((d0 >> 3) & 7);
            vt[d0 * 32 + (((kva >> 3) ^ sv0) & 7) * 4 + ((kva & 6) >> 1)] = pack2(vr0[j], vr1[j]);
            int d1 = dc + 8 + j;
            int sv1 = (d1 & 7) ^ ((d1 >> 3) & 7);
            vt[d1 * 32 + (((kva >> 3) ^ sv1) & 7) * 4 + ((kva & 6) >> 1)] = pack2(vr2[j], vr3[j]);
        }

        __syncthreads();   // drains K-DMA(kt), V writes visible, prev readers done

        // prefetch tile kt+1
        if (kt + 1 < 32) {
            bf16_t* dst = (bf16_t*)(pairBase + ((kt + 1) & 1) * 8192 + w * 4096);
#pragma unroll
            for (int i = 0; i < 4; i++)
                gl_lds16(((i & 1) ? kO : kE) + i * 512, dst + i * 512);
            kE += 4096; kO += 4096;
            int kv0n = (kt + 1) * 64;
            vr0 = ld8(Vp + (size_t)(kv0n + kva) * HD + dc);
            vr1 = ld8(Vp + (size_t)(kv0n + kva + 1) * HD + dc);
            vr2 = ld8(Vp + (size_t)(kv0n + kva) * HD + dc + 8);
            vr3 = ld8(Vp + (size_t)(kv0n + kva + 1) * HD + dc + 8);
        }

        const uint4* kl = (const uint4*)(pairBase + (kt & 1) * 8192);

        f32x4 st[4][4];
        // ---- S for n = 0,1,2 ----
#pragma unroll
        for (int n = 0; n < 3; n++) {
            int kvr = (n >> 1) * 32 + ((c >> 2) * 8) + ((n & 1) * 4) + (c & 3);
            int sk = (kvr & 3) | (((kvr >> 3) & 1) << 2);
            bf16x8 k0 = *reinterpret_cast<const bf16x8*>(&kl[kvr * 8 + (quad ^ sk)]);
            bf16x8 k1 = *reinterpret_cast<const bf16x8*>(&kl[kvr * 8 + ((4 + quad) ^ sk)]);
#pragma unroll
            for (int qt = 0; qt < 4; qt++) {
                f32x4 z = f32x4{0.f, 0.f, 0.f, 0.f};
                z = mfma16(k0, qf[qt][0], z);
                z = mfma16(k1, qf[qt][1], z);
                st[qt][n] = z;
            }
        }

        // ---- softmax-a (n=0,1 -> pf ks=0); overlaps n=2's MFMAs ----
        bf16x8 pfa[4];
#pragma unroll
        for (int qt = 0; qt < 4; qt++) {
            bf16x8 f;
            float ls = 0.f;
#pragma unroll
            for (int j = 0; j < 8; j++) {
                float e = __builtin_amdgcn_exp2f(st[qt][j >> 2][j & 3]);
                ls += e;
                f[j] = (bf16_t)e;
            }
            lsum[qt] += ls;
            pfa[qt] = f;
        }

        // ---- S for n = 3 ----
        {
            const int n = 3;
            int kvr = (n >> 1) * 32 + ((c >> 2) * 8) + ((n & 1) * 4) + (c & 3);
            int sk = (kvr & 3) | (((kvr >> 3) & 1) << 2);
            bf16x8 k0 = *reinterpret_cast<const bf16x8*>(&kl[kvr * 8 + (quad ^ sk)]);
            bf16x8 k1 = *reinterpret_cast<const bf16x8*>(&kl[kvr * 8 + ((4 + quad) ^ sk)]);
#pragma unroll
            for (int qt = 0; qt < 4; qt++) {
                f32x4 z = f32x4{0.f, 0.f, 0.f, 0.f};
                z = mfma16(k0, qf[qt][0], z);
                z = mfma16(k1, qf[qt][1], z);
                st[qt][n] = z;
            }
        }

        // ---- PV ks=0 (uses pfa); overlaps softmax-b's VALU below ----
#pragma unroll
        for (int dt = 0; dt < 4; dt++) {
            int d = dt * 16 + c;
            int sv = (d & 7) ^ ((d >> 3) & 7);
            bf16x8 v0f = *reinterpret_cast<const bf16x8*>(&vt[d * 32 + ((quad ^ sv) & 7) * 4]);
#pragma unroll
            for (int qt = 0; qt < 4; qt++)
                acc[qt][dt] = mfma16(v0f, pfa[qt], acc[qt][dt]);
        }

        // ---- softmax-b (n=2,3 -> pf ks=1) ----
        bf16x8 pfb[4];
#pragma unroll
        for (int qt = 0; qt < 4; qt++) {
            bf16x8 f;
            float ls = 0.f;
#pragma unroll
            for (int j = 0; j < 8; j++) {
                float e = __builtin_amdgcn_exp2f(st[qt][2 + (j >> 2)][j & 3]);
                ls += e;
                f[j] = (bf16_t)e;
            }
            lsum[qt] += ls;
            pfb[qt] = f;
        }

        // ---- PV ks=1 (uses pfb) ----
#pragma unroll
        for (int dt = 0; dt < 4; dt++) {
            int d = dt * 16 + c;
            int sv = (d & 7) ^ ((d >> 3) & 7);
            bf16x8 v1f = *reinterpret_cast<const bf16x8*>(&vt[d * 32 + (((4 + quad) ^ sv) & 7) * 4]);
#pragma unroll
            for (int qt = 0; qt < 4; qt++)
                acc[qt][dt] = mfma16(v1f, pfb[qt], acc[qt][dt]);
        }
    }

    float lred[4];
#pragma unroll
    for (int qt = 0; qt < 4; qt++) {
        float lt = lsum[qt];
        lt += __shfl_xor(lt, 16, 64);
        lt += __shfl_xor(lt, 32, 64);
        lred[qt] = lt;
    }

    // in-block pair-combine via LDS overlay
    __syncthreads();
    float* Ox = (float*)smem;
    float* Lx = (float*)(smem + 128 * 68 * 4);

    if (pr == 1) {
#pragma unroll
        for (int qt = 0; qt < 4; qt++) {
            int ql = w * 64 + qt * 16 + c;
#pragma unroll
            for (int dt = 0; dt < 4; dt++)
                *reinterpret_cast<f32x4*>(&Ox[ql * 68 + dt * 16 + quad * 4]) = acc[qt][dt];
            if (quad == 0) Lx[ql] = lred[qt];
        }
    }
    __syncthreads();
    if (pr == 0) {
        int b_ = bh >> 3, h = bh & 7;
#pragma unroll
        for (int qt = 0; qt < 4; qt++) {
            int ql = w * 64 + qt * 16 + c;
            float inv_l = 1.0f / (lred[qt] + Lx[ql]);
            int srow = qw + qt * 16 + c;
            bf16_t* yrow = Y + (size_t)(b_ * SEQ + srow) * DMODEL + h * HD;
#pragma unroll
            for (int dt = 0; dt < 4; dt++) {
                f32x4 o4 = acc[qt][dt] + *reinterpret_cast<const f32x4*>(&Ox[ql * 68 + dt * 16 + quad * 4]);
                bf16x4 o;
#pragma unroll
                for (int r = 0; r < 4; r++) o[r] = (bf16_t)(o4[r] * inv_l);
                *reinterpret_cast<bf16x4*>(yrow + dt * 16 + quad * 4) = o;
            }
        }
    }
}

extern "C" void kernel_launch(void* const* d_in, const int* in_sizes, int n_in,
                              void* d_out, int out_size, void* d_ws, size_t ws_size,
                              hipStream_t stream) {
    (void)in_sizes; (void)n_in; (void)out_size; (void)ws_size;
    const float* x  = (const float*)d_in[0];
    const float* Wq = (const float*)d_in[1];
    const float* Wk = (const float*)d_in[2];
    const float* Wv = (const float*)d_in[3];
    const float* Wo = (const float*)d_in[4];
    const int*   Vp = (const int*)d_in[6];
    float* out = (float*)d_out;

    bf16_t* ws  = (bf16_t*)d_ws;
    bf16_t* Xb  = ws;                    // 8192*512
    bf16_t* Wc  = Xb  + 4194304;         // [Wq|Wk|Wv]
    bf16_t* Wob = Wc  + 786432;
    bf16_t* Qb  = Wob + 262144;
    bf16_t* Kb  = Qb  + 4194304;
    bf16_t* Vb  = Kb  + 4194304;
    bf16_t* Yb  = Vb  + 4194304;

    cast_all<<<5120, 256, 0, stream>>>(x, Wq, Wk, Wv, Wo, Xb, Wc, Wob);

    gemm_qkv<<<dim3(64, 12), 256, 0, stream>>>(Xb, Wc, Qb, Kb, Vb, Vp);

    flash_attn<<<dim3(32, 16), 256, 0, stream>>>(Qb, Kb, Vb, Yb);

    gemm_out<<<dim3(64, 8), 256, 0, stream>>>(Yb, Wob, out);
}

// Round 14
// 212.358 us; speedup vs baseline: 1.2691x; 1.2691x over previous
//
#include <hip/hip_runtime.h>
#include <hip/hip_bf16.h>

#define SEQ 4096
#define BSZ 2
#define NH 8
#define HD 64
#define DMODEL 512

typedef __bf16 bf16_t;
typedef __bf16 bf16x8 __attribute__((ext_vector_type(8)));
typedef __bf16 bf16x4 __attribute__((ext_vector_type(4)));
typedef float f32x4 __attribute__((ext_vector_type(4)));

__device__ __forceinline__ f32x4 mfma16(bf16x8 a, bf16x8 b, f32x4 c) {
    return __builtin_amdgcn_mfma_f32_16x16x32_bf16(a, b, c, 0, 0, 0);
}

__device__ __forceinline__ bf16x8 ld8(const bf16_t* p) {
    return *reinterpret_cast<const bf16x8*>(p);
}

__device__ __forceinline__ uint32_t pack2(bf16_t a, bf16_t b) {
    union { bf16_t h[2]; uint32_t u; } x;
    x.h[0] = a; x.h[1] = b;
    return x.u;
}

// async global->LDS DMA, 16 B/lane; data lands at lds base + lane*16
__device__ __forceinline__ void gl_lds16(const bf16_t* g, bf16_t* l) {
    __builtin_amdgcn_global_load_lds(
        (const __attribute__((address_space(1))) uint32_t*)g,
        (__attribute__((address_space(3))) uint32_t*)l,
        16, 0, 0);
}

// ---------------- fused cast fp32 -> bf16 (x + all 4 weights) ----------------
__global__ void cast_all(const float* __restrict__ x,
                         const float* __restrict__ wq, const float* __restrict__ wk,
                         const float* __restrict__ wv, const float* __restrict__ wo,
                         bf16_t* __restrict__ Xb, bf16_t* __restrict__ Wc,
                         bf16_t* __restrict__ Wob) {
    int i = blockIdx.x * blockDim.x + threadIdx.x;
    const float* src;
    bf16_t* dst;
    int j;
    if (i < 1048576) { src = x; dst = Xb; j = i; }
    else {
        int k = i - 1048576;
        int w = k >> 16;
        j = k & 65535;
        src = (w == 0) ? wq : (w == 1) ? wk : (w == 2) ? wv : wo;
        dst = (w == 3) ? Wob : Wc + w * 262144;
    }
    float4 v = reinterpret_cast<const float4*>(src)[j];
    bf16x4 o;
    o[0] = (bf16_t)v.x; o[1] = (bf16_t)v.y; o[2] = (bf16_t)v.z; o[3] = (bf16_t)v.w;
    reinterpret_cast<bf16x4*>(dst)[j] = o;
}

// ---------------- m97-style GEMM core (128x128) ----------------
__device__ __forceinline__ void gemm_core_128(const bf16_t* __restrict__ A,
                                              const bf16_t* __restrict__ B,
                                              int m0, int n0,
                                              bf16_t* As, bf16_t* Bs,
                                              f32x4 acc[4][4]) {
    const int t = threadIdx.x;
    const int lane = t & 63;
    const int wid = t >> 6;
    const int c = lane & 15, quad = lane >> 4;
    const int wm = wid & 1, wn = wid >> 1;

#pragma unroll
    for (int i = 0; i < 4; i++)
#pragma unroll
        for (int j = 0; j < 4; j++) acc[i][j] = f32x4{0.f, 0.f, 0.f, 0.f};

    const int lrow = lane >> 2;
    const int lch = lane & 3;
    const bf16_t* Ag = A + (size_t)(m0 + wid * 32 + lrow) * 512 + lch * 8;
    const bf16_t* Bg = B + (size_t)(n0 + wid * 32 + lrow) * 512 + lch * 8;
    bf16_t* Asw0 = As + (wid * 32) * 32;
    bf16_t* Asw1 = As + (wid * 32 + 16) * 32;
    bf16_t* Bsw0 = Bs + (wid * 32) * 32;
    bf16_t* Bsw1 = Bs + (wid * 32 + 16) * 32;

    for (int k0 = 0; k0 < 512; k0 += 32) {
        gl_lds16(Ag + k0, Asw0);
        gl_lds16(Ag + 16 * 512 + k0, Asw1);
        gl_lds16(Bg + k0, Bsw0);
        gl_lds16(Bg + 16 * 512 + k0, Bsw1);
        __syncthreads();

        bf16x8 a[4], b[4];
#pragma unroll
        for (int i = 0; i < 4; i++) a[i] = ld8(&As[(wm * 64 + i * 16 + c) * 32 + quad * 8]);
#pragma unroll
        for (int j = 0; j < 4; j++) b[j] = ld8(&Bs[(wn * 64 + j * 16 + c) * 32 + quad * 8]);
#pragma unroll
        for (int i = 0; i < 4; i++)
#pragma unroll
            for (int j = 0; j < 4; j++) acc[i][j] = mfma16(a[i], b[j], acc[i][j]);

        __syncthreads();
    }
}

// ---------------- GEMM1 + fused RoPE epilogue ----------------
__global__ __launch_bounds__(256) void gemm_qkv(const bf16_t* __restrict__ A,
                                                const bf16_t* __restrict__ W,
                                                bf16_t* __restrict__ Qb,
                                                bf16_t* __restrict__ Kb,
                                                bf16_t* __restrict__ Vb,
                                                const int* __restrict__ Vpar) {
    __shared__ bf16_t As[128 * 32];
    __shared__ bf16_t Bs[128 * 32];
    const int lane = threadIdx.x & 63;
    const int wid = threadIdx.x >> 6;
    const int c = lane & 15, quad = lane >> 4;
    const int wm = wid & 1, wn = wid >> 1;
    const int m0 = blockIdx.x * 128;
    const int n0 = blockIdx.y * 128;

    f32x4 acc[4][4];
    gemm_core_128(A, W, m0, n0, As, Bs, acc);

    const int Vv = Vpar[0];
    const float qs = 0.1803368801111204f;   // 0.125 * log2(e)

#pragma unroll
    for (int i = 0; i < 4; i++) {
        int mbase = m0 + wm * 64 + i * 16 + quad * 4;
#pragma unroll
        for (int j = 0; j < 4; j++) {
            int col = n0 + wn * 64 + j * 16 + c;
            int which = col >> 9;            // uniform per (wave, j)
            int h = (col >> 6) & 7;
            int d = col & 63;
            f32x4 v = acc[i][j];
            if (which < 2) {                 // rope Q / K (wave-uniform branch)
                int fidx = (d & 31) >> 1;
                float inv = exp2f((float)fidx * -0.8304820237218407f);
                bool hi = (d >= 32);
                bool odd = (d & 1);
                f32x4 part;
#pragma unroll
                for (int r = 0; r < 4; r++) part[r] = __shfl_xor(v[r], 1, 64);
#pragma unroll
                for (int r = 0; r < 4; r++) {
                    int s = (mbase + r) & 4095;
                    int tq = s / Vv;
                    int vq = s - tq * Vv;
                    float ang = (float)(hi ? vq : tq) * inv;
                    float sn = __sinf(ang), cs = __cosf(ang);
                    float xe = odd ? part[r] : v[r];
                    float xo = odd ? v[r] : part[r];
                    v[r] = odd ? (xe * sn + xo * cs) : (xe * cs - xo * sn);
                }
                if (which == 0) {
#pragma unroll
                    for (int r = 0; r < 4; r++) v[r] *= qs;
                }
            }
            bf16_t* dst = (which == 0) ? Qb : ((which == 1) ? Kb : Vb);
#pragma unroll
            for (int r = 0; r < 4; r++) {
                int m = mbase + r;
                int b_ = m >> 12;
                int s = m & 4095;
                dst[((size_t)(b_ * NH + h) * SEQ + s) * HD + d] = (bf16_t)v[r];
            }
        }
    }
}

// ---------------- GEMM2: 128x64 tiles, grid (64,8) ----------------
__global__ __launch_bounds__(256) void gemm_out(const bf16_t* __restrict__ A,
                                                const bf16_t* __restrict__ W,
                                                float* __restrict__ out) {
    __shared__ bf16_t As[128 * 32];
    __shared__ bf16_t Bs[64 * 32];
    const int t = threadIdx.x;
    const int lane = t & 63;
    const int wid = t >> 6;
    const int c = lane & 15, quad = lane >> 4;
    const int m0 = blockIdx.x * 128;
    const int n0 = blockIdx.y * 64;

    f32x4 acc[2][4];
#pragma unroll
    for (int i = 0; i < 2; i++)
#pragma unroll
        for (int j = 0; j < 4; j++) acc[i][j] = f32x4{0.f, 0.f, 0.f, 0.f};

    const int lrow = lane >> 2;
    const int lch = lane & 3;
    const bf16_t* Ag = A + (size_t)(m0 + wid * 32 + lrow) * 512 + lch * 8;
    const bf16_t* Bg = W + (size_t)(n0 + wid * 16 + lrow) * 512 + lch * 8;
    bf16_t* Asw0 = As + (wid * 32) * 32;
    bf16_t* Asw1 = As + (wid * 32 + 16) * 32;
    bf16_t* Bsw = Bs + (wid * 16) * 32;

    for (int k0 = 0; k0 < 512; k0 += 32) {
        gl_lds16(Ag + k0, Asw0);
        gl_lds16(Ag + 16 * 512 + k0, Asw1);
        gl_lds16(Bg + k0, Bsw);
        __syncthreads();

        bf16x8 a[2], b[4];
#pragma unroll
        for (int i = 0; i < 2; i++) a[i] = ld8(&As[(wid * 32 + i * 16 + c) * 32 + quad * 8]);
#pragma unroll
        for (int j = 0; j < 4; j++) b[j] = ld8(&Bs[(j * 16 + c) * 32 + quad * 8]);
#pragma unroll
        for (int i = 0; i < 2; i++)
#pragma unroll
            for (int j = 0; j < 4; j++) acc[i][j] = mfma16(a[i], b[j], acc[i][j]);

        __syncthreads();
    }

#pragma unroll
    for (int i = 0; i < 2; i++) {
        int mbase = m0 + wid * 32 + i * 16 + quad * 4;
#pragma unroll
        for (int j = 0; j < 4; j++) {
            int col = n0 + j * 16 + c;
#pragma unroll
            for (int r = 0; r < 4; r++)
                out[(size_t)(mbase + r) * DMODEL + col] = acc[i][j][r];
        }
    }
}

// ---------------- Flash attention (r12 known-good: 102.5 us) ----------------
// 256 thr = 4 waves; wave-pair pr sweeps kv half (2048), 64 q/wave (qt=4).
// K: double-buffered global_load_lds with XOR-swizzle applied on SOURCE
//    addresses — no kreg, no K ds_writes.
// V: double-buffered reg-prefetch + transposed/swizzled ds_writes.
// 1 barrier/iter. No max-subtraction softmax (exp2 domain, scale in Q).
// Reg-file-bound at 2 waves/SIMD (128 arch + 64 AGPR = 192, 64-reg
// granules). Do NOT reorder compute phases (r13: manual interleave
// defeated compiler scheduling, 102->158 us) and do NOT raise
// launch_bounds w (r5/r7: budget 512/w, w=4 => spill disaster).
__global__ __launch_bounds__(256, 2) void flash_attn(const bf16_t* __restrict__ Q,
                                                     const bf16_t* __restrict__ K,
                                                     const bf16_t* __restrict__ V,
                                                     bf16_t* __restrict__ Y) {
    // per pair 32768 B: K buf0 8K | K buf1 8K | V^T buf0 8K | V^T buf1 8K
    __shared__ __align__(16) unsigned char smem[65536];

    const int t = threadIdx.x;
    const int lane = t & 63;
    const int c = lane & 15, quad = lane >> 4;
    const int wid = t >> 6;            // 0..3
    const int w = wid & 1;             // q-wave id == K-stage half id
    const int pr = wid >> 1;           // kv pair 0/1
    const int bh = blockIdx.y;
    const int qw = blockIdx.x * 128 + w * 64;

    size_t base = (size_t)bh * SEQ * HD;
    const bf16_t* Qp = Q + base;
    const bf16_t* Vp = V + base + (size_t)pr * 2048 * HD;

    unsigned char* pairBase = smem + pr * 32768;

    // K DMA swizzled source pointers: wave w stages tile rows [w*32, w*32+32)
    // in 4 calls x 8 rows; call parity flips chunk bit2 (kO = kE ^ 64 B).
    const bf16_t* Kpb = K + base + (size_t)pr * 2048 * HD;
    int srcOff = w * 4096 + ((lane >> 3) * 128) +
                 (((lane & 7) ^ ((lane >> 3) & 3)) * 16);
    const bf16_t* kE = (const bf16_t*)((const unsigned char*)Kpb + srcOff);
    const bf16_t* kO = (const bf16_t*)((const unsigned char*)Kpb + (srcOff ^ 64));

    bf16x8 qf[4][2];
#pragma unroll
    for (int qt = 0; qt < 4; qt++)
#pragma unroll
        for (int ks = 0; ks < 2; ks++)
            qf[qt][ks] = ld8(Qp + (size_t)(qw + qt * 16 + c) * HD + ks * 32 + quad * 8);

    f32x4 acc[4][4];
#pragma unroll
    for (int qt = 0; qt < 4; qt++)
#pragma unroll
        for (int dt = 0; dt < 4; dt++) acc[qt][dt] = f32x4{0.f, 0.f, 0.f, 0.f};
    float lsum[4] = {0.f, 0.f, 0.f, 0.f};

    // V staging (pair's 128 threads): rows kva,kva+1, d in [dc, dc+16)
    const int tp = t & 127;
    const int kva = 2 * (tp & 31);
    const int dc = 16 * (tp >> 5);

    // pre-loop: K tile 0 DMA into buf0; V tile 0 into regs
    {
        bf16_t* dst = (bf16_t*)(pairBase + w * 4096);
#pragma unroll
        for (int i = 0; i < 4; i++)
            gl_lds16(((i & 1) ? kO : kE) + i * 512, dst + i * 512);
        kE += 4096; kO += 4096;
    }
    bf16x8 vr0 = ld8(Vp + (size_t)kva * HD + dc);
    bf16x8 vr1 = ld8(Vp + (size_t)(kva + 1) * HD + dc);
    bf16x8 vr2 = ld8(Vp + (size_t)kva * HD + dc + 8);
    bf16x8 vr3 = ld8(Vp + (size_t)(kva + 1) * HD + dc + 8);

    for (int kt = 0; kt < 32; kt++) {
        uint32_t* vt = (uint32_t*)(pairBase + 16384 + (kt & 1) * 8192);

        // V transpose+swizzle stage for tile kt
#pragma unroll
        for (int j = 0; j < 8; j++) {
            int d0 = dc + j;
            int sv0 = (d0 & 7) ^ ((d0 >> 3) & 7);
            vt[d0 * 32 + (((kva >> 3) ^ sv0) & 7) * 4 + ((kva & 6) >> 1)] = pack2(vr0[j], vr1[j]);
            int d1 = dc + 8 + j;
            int sv1 = (d1 & 7) ^ ((d1 >> 3) & 7);
            vt[d1 * 32 + (((kva >> 3) ^ sv1) & 7) * 4 + ((kva & 6) >> 1)] = pack2(vr2[j], vr3[j]);
        }

        __syncthreads();   // drains K-DMA(kt), V writes visible, prev readers done

        // prefetch tile kt+1: K via DMA into other buf, V into regs
        if (kt + 1 < 32) {
            bf16_t* dst = (bf16_t*)(pairBase + ((kt + 1) & 1) * 8192 + w * 4096);
#pragma unroll
            for (int i = 0; i < 4; i++)
                gl_lds16(((i & 1) ? kO : kE) + i * 512, dst + i * 512);
            kE += 4096; kO += 4096;
            int kv0n = (kt + 1) * 64;
            vr0 = ld8(Vp + (size_t)(kv0n + kva) * HD + dc);
            vr1 = ld8(Vp + (size_t)(kv0n + kva + 1) * HD + dc);
            vr2 = ld8(Vp + (size_t)(kv0n + kva) * HD + dc + 8);
            vr3 = ld8(Vp + (size_t)(kv0n + kva + 1) * HD + dc + 8);
        }

        const uint4* kl = (const uint4*)(pairBase + (kt & 1) * 8192);

        // S^T = K*Q^T, kv-permuted rows
        f32x4 st[4][4];
#pragma unroll
        for (int n = 0; n < 4; n++) {
            int kvr = (n >> 1) * 32 + ((c >> 2) * 8) + ((n & 1) * 4) + (c & 3);
            int sk = (kvr & 3) | (((kvr >> 3) & 1) << 2);
            bf16x8 k0 = *reinterpret_cast<const bf16x8*>(&kl[kvr * 8 + (quad ^ sk)]);
            bf16x8 k1 = *reinterpret_cast<const bf16x8*>(&kl[kvr * 8 + ((4 + quad) ^ sk)]);
#pragma unroll
            for (int qt = 0; qt < 4; qt++) {
                f32x4 z = f32x4{0.f, 0.f, 0.f, 0.f};
                z = mfma16(k0, qf[qt][0], z);
                z = mfma16(k1, qf[qt][1], z);
                st[qt][n] = z;
            }
        }

        // softmax without max-subtraction (exp2 domain)
        bf16x8 pf[4][2];
#pragma unroll
        for (int qt = 0; qt < 4; qt++) {
            float e[4][4];
            float ls = 0.f;
#pragma unroll
            for (int n = 0; n < 4; n++)
#pragma unroll
                for (int r = 0; r < 4; r++) {
                    float v = __builtin_amdgcn_exp2f(st[qt][n][r]);
                    e[n][r] = v;
                    ls += v;
                }
            lsum[qt] += ls;
            bf16x8 f0, f1;
#pragma unroll
            for (int j = 0; j < 8; j++) {
                f0[j] = (bf16_t)e[(j >> 2)][j & 3];
                f1[j] = (bf16_t)e[2 + (j >> 2)][j & 3];
            }
            pf[qt][0] = f0;
            pf[qt][1] = f1;
        }

        // O^T += V^T * P^T
#pragma unroll
        for (int dt = 0; dt < 4; dt++) {
            int d = dt * 16 + c;
            int sv = (d & 7) ^ ((d >> 3) & 7);
            bf16x8 v0f = *reinterpret_cast<const bf16x8*>(&vt[d * 32 + ((quad ^ sv) & 7) * 4]);
            bf16x8 v1f = *reinterpret_cast<const bf16x8*>(&vt[d * 32 + (((4 + quad) ^ sv) & 7) * 4]);
#pragma unroll
            for (int qt = 0; qt < 4; qt++) {
                acc[qt][dt] = mfma16(v0f, pf[qt][0], acc[qt][dt]);
                acc[qt][dt] = mfma16(v1f, pf[qt][1], acc[qt][dt]);
            }
        }
    }

    float lred[4];
#pragma unroll
    for (int qt = 0; qt < 4; qt++) {
        float lt = lsum[qt];
        lt += __shfl_xor(lt, 16, 64);
        lt += __shfl_xor(lt, 32, 64);
        lred[qt] = lt;
    }

    // in-block pair-combine via LDS overlay
    __syncthreads();
    float* Ox = (float*)smem;
    float* Lx = (float*)(smem + 128 * 68 * 4);

    if (pr == 1) {
#pragma unroll
        for (int qt = 0; qt < 4; qt++) {
            int ql = w * 64 + qt * 16 + c;
#pragma unroll
            for (int dt = 0; dt < 4; dt++)
                *reinterpret_cast<f32x4*>(&Ox[ql * 68 + dt * 16 + quad * 4]) = acc[qt][dt];
            if (quad == 0) Lx[ql] = lred[qt];
        }
    }
    __syncthreads();
    if (pr == 0) {
        int b_ = bh >> 3, h = bh & 7;
#pragma unroll
        for (int qt = 0; qt < 4; qt++) {
            int ql = w * 64 + qt * 16 + c;
            float inv_l = 1.0f / (lred[qt] + Lx[ql]);
            int srow = qw + qt * 16 + c;
            bf16_t* yrow = Y + (size_t)(b_ * SEQ + srow) * DMODEL + h * HD;
#pragma unroll
            for (int dt = 0; dt < 4; dt++) {
                f32x4 o4 = acc[qt][dt] + *reinterpret_cast<const f32x4*>(&Ox[ql * 68 + dt * 16 + quad * 4]);
                bf16x4 o;
#pragma unroll
                for (int r = 0; r < 4; r++) o[r] = (bf16_t)(o4[r] * inv_l);
                *reinterpret_cast<bf16x4*>(yrow + dt * 16 + quad * 4) = o;
            }
        }
    }
}

extern "C" void kernel_launch(void* const* d_in, const int* in_sizes, int n_in,
                              void* d_out, int out_size, void* d_ws, size_t ws_size,
                              hipStream_t stream) {
    (void)in_sizes; (void)n_in; (void)out_size; (void)ws_size;
    const float* x  = (const float*)d_in[0];
    const float* Wq = (const float*)d_in[1];
    const float* Wk = (const float*)d_in[2];
    const float* Wv = (const float*)d_in[3];
    const float* Wo = (const float*)d_in[4];
    const int*   Vp = (const int*)d_in[6];
    float* out = (float*)d_out;

    bf16_t* ws  = (bf16_t*)d_ws;
    bf16_t* Xb  = ws;                    // 8192*512
    bf16_t* Wc  = Xb  + 4194304;         // [Wq|Wk|Wv]
    bf16_t* Wob = Wc  + 786432;
    bf16_t* Qb  = Wob + 262144;
    bf16_t* Kb  = Qb  + 4194304;
    bf16_t* Vb  = Kb  + 4194304;
    bf16_t* Yb  = Vb  + 4194304;

    cast_all<<<5120, 256, 0, stream>>>(x, Wq, Wk, Wv, Wo, Xb, Wc, Wob);

    gemm_qkv<<<dim3(64, 12), 256, 0, stream>>>(Xb, Wc, Qb, Kb, Vb, Vp);

    flash_attn<<<dim3(32, 16), 256, 0, stream>>>(Qb, Kb, Vb, Yb);

    gemm_out<<<dim3(64, 8), 256, 0, stream>>>(Yb, Wob, out);
}

// Round 15
// 206.231 us; speedup vs baseline: 1.3068x; 1.0297x over previous
//
#include <hip/hip_runtime.h>
#include <hip/hip_bf16.h>

#define SEQ 4096
#define BSZ 2
#define NH 8
#define HD 64
#define DMODEL 512

typedef __bf16 bf16_t;
typedef __bf16 bf16x8 __attribute__((ext_vector_type(8)));
typedef __bf16 bf16x4 __attribute__((ext_vector_type(4)));
typedef float f32x4 __attribute__((ext_vector_type(4)));

__device__ __forceinline__ f32x4 mfma16(bf16x8 a, bf16x8 b, f32x4 c) {
    return __builtin_amdgcn_mfma_f32_16x16x32_bf16(a, b, c, 0, 0, 0);
}

__device__ __forceinline__ bf16x8 ld8(const bf16_t* p) {
    return *reinterpret_cast<const bf16x8*>(p);
}

__device__ __forceinline__ uint32_t pack2(bf16_t a, bf16_t b) {
    union { bf16_t h[2]; uint32_t u; } x;
    x.h[0] = a; x.h[1] = b;
    return x.u;
}

// async global->LDS DMA, 16 B/lane; data lands at lds base + lane*16
__device__ __forceinline__ void gl_lds16(const bf16_t* g, bf16_t* l) {
    __builtin_amdgcn_global_load_lds(
        (const __attribute__((address_space(1))) uint32_t*)g,
        (__attribute__((address_space(3))) uint32_t*)l,
        16, 0, 0);
}

// ---------------- fused cast fp32 -> bf16 (x + all 4 weights) ----------------
__global__ void cast_all(const float* __restrict__ x,
                         const float* __restrict__ wq, const float* __restrict__ wk,
                         const float* __restrict__ wv, const float* __restrict__ wo,
                         bf16_t* __restrict__ Xb, bf16_t* __restrict__ Wc,
                         bf16_t* __restrict__ Wob) {
    int i = blockIdx.x * blockDim.x + threadIdx.x;
    const float* src;
    bf16_t* dst;
    int j;
    if (i < 1048576) { src = x; dst = Xb; j = i; }
    else {
        int k = i - 1048576;
        int w = k >> 16;
        j = k & 65535;
        src = (w == 0) ? wq : (w == 1) ? wk : (w == 2) ? wv : wo;
        dst = (w == 3) ? Wob : Wc + w * 262144;
    }
    float4 v = reinterpret_cast<const float4*>(src)[j];
    bf16x4 o;
    o[0] = (bf16_t)v.x; o[1] = (bf16_t)v.y; o[2] = (bf16_t)v.z; o[3] = (bf16_t)v.w;
    reinterpret_cast<bf16x4*>(dst)[j] = o;
}

// ---------------- GEMM1 + fused RoPE epilogue (double-buffered staging) ----------------
// Dbuf pattern (validated by r12 flash K-staging): barrier drains DMA(k),
// then DMA(k+1) into other buffer is issued and flies over MFMA(k).
// 1 barrier/iter (vs r14's 2 with zero overlap).
__global__ __launch_bounds__(256) void gemm_qkv(const bf16_t* __restrict__ A,
                                                const bf16_t* __restrict__ W,
                                                bf16_t* __restrict__ Qb,
                                                bf16_t* __restrict__ Kb,
                                                bf16_t* __restrict__ Vb,
                                                const int* __restrict__ Vpar) {
    __shared__ bf16_t As[2 * 128 * 32];   // 16 KB
    __shared__ bf16_t Bs[2 * 128 * 32];   // 16 KB
    const int lane = threadIdx.x & 63;
    const int wid = threadIdx.x >> 6;
    const int c = lane & 15, quad = lane >> 4;
    const int wm = wid & 1, wn = wid >> 1;
    const int m0 = blockIdx.x * 128;
    const int n0 = blockIdx.y * 128;

    f32x4 acc[4][4];
#pragma unroll
    for (int i = 0; i < 4; i++)
#pragma unroll
        for (int j = 0; j < 4; j++) acc[i][j] = f32x4{0.f, 0.f, 0.f, 0.f};

    const int lrow = lane >> 2;
    const int lch = lane & 3;
    const bf16_t* Ag = A + (size_t)(m0 + wid * 32 + lrow) * 512 + lch * 8;
    const bf16_t* Bg = W + (size_t)(n0 + wid * 32 + lrow) * 512 + lch * 8;
    const int w0 = (wid * 32) * 32;
    const int w1 = (wid * 32 + 16) * 32;

    // pre-loop: tile 0 into buf 0
    gl_lds16(Ag, As + w0);
    gl_lds16(Ag + 16 * 512, As + w1);
    gl_lds16(Bg, Bs + w0);
    gl_lds16(Bg + 16 * 512, Bs + w1);

    for (int it = 0; it < 16; it++) {
        __syncthreads();   // drains DMA(it); readers of buf[it-1] done

        if (it + 1 < 16) {
            int k0 = (it + 1) * 32;
            int bo = ((it + 1) & 1) * 4096;
            gl_lds16(Ag + k0, As + bo + w0);
            gl_lds16(Ag + 16 * 512 + k0, As + bo + w1);
            gl_lds16(Bg + k0, Bs + bo + w0);
            gl_lds16(Bg + 16 * 512 + k0, Bs + bo + w1);
        }

        const bf16_t* Ab = As + (it & 1) * 4096;
        const bf16_t* Bb = Bs + (it & 1) * 4096;
        bf16x8 a[4], b[4];
#pragma unroll
        for (int i = 0; i < 4; i++) a[i] = ld8(&Ab[(wm * 64 + i * 16 + c) * 32 + quad * 8]);
#pragma unroll
        for (int j = 0; j < 4; j++) b[j] = ld8(&Bb[(wn * 64 + j * 16 + c) * 32 + quad * 8]);
#pragma unroll
        for (int i = 0; i < 4; i++)
#pragma unroll
            for (int j = 0; j < 4; j++) acc[i][j] = mfma16(a[i], b[j], acc[i][j]);
    }

    const int Vv = Vpar[0];
    const float qs = 0.1803368801111204f;   // 0.125 * log2(e)

#pragma unroll
    for (int i = 0; i < 4; i++) {
        int mbase = m0 + wm * 64 + i * 16 + quad * 4;
#pragma unroll
        for (int j = 0; j < 4; j++) {
            int col = n0 + wn * 64 + j * 16 + c;
            int which = col >> 9;            // uniform per (wave, j)
            int h = (col >> 6) & 7;
            int d = col & 63;
            f32x4 v = acc[i][j];
            if (which < 2) {                 // rope Q / K (wave-uniform branch)
                int fidx = (d & 31) >> 1;
                float inv = exp2f((float)fidx * -0.8304820237218407f);
                bool hi = (d >= 32);
                bool odd = (d & 1);
                f32x4 part;
#pragma unroll
                for (int r = 0; r < 4; r++) part[r] = __shfl_xor(v[r], 1, 64);
#pragma unroll
                for (int r = 0; r < 4; r++) {
                    int s = (mbase + r) & 4095;
                    int tq = s / Vv;
                    int vq = s - tq * Vv;
                    float ang = (float)(hi ? vq : tq) * inv;
                    float sn = __sinf(ang), cs = __cosf(ang);
                    float xe = odd ? part[r] : v[r];
                    float xo = odd ? v[r] : part[r];
                    v[r] = odd ? (xe * sn + xo * cs) : (xe * cs - xo * sn);
                }
                if (which == 0) {
#pragma unroll
                    for (int r = 0; r < 4; r++) v[r] *= qs;
                }
            }
            bf16_t* dst = (which == 0) ? Qb : ((which == 1) ? Kb : Vb);
#pragma unroll
            for (int r = 0; r < 4; r++) {
                int m = mbase + r;
                int b_ = m >> 12;
                int s = m & 4095;
                dst[((size_t)(b_ * NH + h) * SEQ + s) * HD + d] = (bf16_t)v[r];
            }
        }
    }
}

// ---------------- GEMM2: 128x64 tiles, dbuf staging, grid (64,8) ----------------
__global__ __launch_bounds__(256) void gemm_out(const bf16_t* __restrict__ A,
                                                const bf16_t* __restrict__ W,
                                                float* __restrict__ out) {
    __shared__ bf16_t As[2 * 128 * 32];   // 16 KB
    __shared__ bf16_t Bs[2 * 64 * 32];    // 8 KB
    const int t = threadIdx.x;
    const int lane = t & 63;
    const int wid = t >> 6;
    const int c = lane & 15, quad = lane >> 4;
    const int m0 = blockIdx.x * 128;
    const int n0 = blockIdx.y * 64;

    f32x4 acc[2][4];
#pragma unroll
    for (int i = 0; i < 2; i++)
#pragma unroll
        for (int j = 0; j < 4; j++) acc[i][j] = f32x4{0.f, 0.f, 0.f, 0.f};

    const int lrow = lane >> 2;
    const int lch = lane & 3;
    const bf16_t* Ag = A + (size_t)(m0 + wid * 32 + lrow) * 512 + lch * 8;
    const bf16_t* Bg = W + (size_t)(n0 + wid * 16 + lrow) * 512 + lch * 8;
    const int aw0 = (wid * 32) * 32;
    const int aw1 = (wid * 32 + 16) * 32;
    const int bw = (wid * 16) * 32;

    gl_lds16(Ag, As + aw0);
    gl_lds16(Ag + 16 * 512, As + aw1);
    gl_lds16(Bg, Bs + bw);

    for (int it = 0; it < 16; it++) {
        __syncthreads();

        if (it + 1 < 16) {
            int k0 = (it + 1) * 32;
            int ao = ((it + 1) & 1) * 4096;
            int bo = ((it + 1) & 1) * 2048;
            gl_lds16(Ag + k0, As + ao + aw0);
            gl_lds16(Ag + 16 * 512 + k0, As + ao + aw1);
            gl_lds16(Bg + k0, Bs + bo + bw);
        }

        const bf16_t* Ab = As + (it & 1) * 4096;
        const bf16_t* Bb = Bs + (it & 1) * 2048;
        bf16x8 a[2], b[4];
#pragma unroll
        for (int i = 0; i < 2; i++) a[i] = ld8(&Ab[(wid * 32 + i * 16 + c) * 32 + quad * 8]);
#pragma unroll
        for (int j = 0; j < 4; j++) b[j] = ld8(&Bb[(j * 16 + c) * 32 + quad * 8]);
#pragma unroll
        for (int i = 0; i < 2; i++)
#pragma unroll
            for (int j = 0; j < 4; j++) acc[i][j] = mfma16(a[i], b[j], acc[i][j]);
    }

#pragma unroll
    for (int i = 0; i < 2; i++) {
        int mbase = m0 + wid * 32 + i * 16 + quad * 4;
#pragma unroll
        for (int j = 0; j < 4; j++) {
            int col = n0 + j * 16 + c;
#pragma unroll
            for (int r = 0; r < 4; r++)
                out[(size_t)(mbase + r) * DMODEL + col] = acc[i][j][r];
        }
    }
}

// ---------------- Flash attention (r12 known-good: 102.5 us) ----------------
// 256 thr = 4 waves; wave-pair pr sweeps kv half (2048), 64 q/wave (qt=4).
// K: double-buffered global_load_lds with XOR-swizzle applied on SOURCE
//    addresses — no kreg, no K ds_writes.
// V: double-buffered reg-prefetch + transposed/swizzled ds_writes.
// 1 barrier/iter. No max-subtraction softmax (exp2 domain, scale in Q).
// Reg-file-bound at 2 waves/SIMD (128 arch + 64 AGPR = 192, 64-reg
// granules). Do NOT reorder compute phases (r13: manual interleave
// defeated compiler scheduling, 102->158 us) and do NOT raise
// launch_bounds w (r5/r7: budget 512/w, w=4 => spill disaster).
__global__ __launch_bounds__(256, 2) void flash_attn(const bf16_t* __restrict__ Q,
                                                     const bf16_t* __restrict__ K,
                                                     const bf16_t* __restrict__ V,
                                                     bf16_t* __restrict__ Y) {
    // per pair 32768 B: K buf0 8K | K buf1 8K | V^T buf0 8K | V^T buf1 8K
    __shared__ __align__(16) unsigned char smem[65536];

    const int t = threadIdx.x;
    const int lane = t & 63;
    const int c = lane & 15, quad = lane >> 4;
    const int wid = t >> 6;            // 0..3
    const int w = wid & 1;             // q-wave id == K-stage half id
    const int pr = wid >> 1;           // kv pair 0/1
    const int bh = blockIdx.y;
    const int qw = blockIdx.x * 128 + w * 64;

    size_t base = (size_t)bh * SEQ * HD;
    const bf16_t* Qp = Q + base;
    const bf16_t* Vp = V + base + (size_t)pr * 2048 * HD;

    unsigned char* pairBase = smem + pr * 32768;

    // K DMA swizzled source pointers: wave w stages tile rows [w*32, w*32+32)
    // in 4 calls x 8 rows; call parity flips chunk bit2 (kO = kE ^ 64 B).
    const bf16_t* Kpb = K + base + (size_t)pr * 2048 * HD;
    int srcOff = w * 4096 + ((lane >> 3) * 128) +
                 (((lane & 7) ^ ((lane >> 3) & 3)) * 16);
    const bf16_t* kE = (const bf16_t*)((const unsigned char*)Kpb + srcOff);
    const bf16_t* kO = (const bf16_t*)((const unsigned char*)Kpb + (srcOff ^ 64));

    bf16x8 qf[4][2];
#pragma unroll
    for (int qt = 0; qt < 4; qt++)
#pragma unroll
        for (int ks = 0; ks < 2; ks++)
            qf[qt][ks] = ld8(Qp + (size_t)(qw + qt * 16 + c) * HD + ks * 32 + quad * 8);

    f32x4 acc[4][4];
#pragma unroll
    for (int qt = 0; qt < 4; qt++)
#pragma unroll
        for (int dt = 0; dt < 4; dt++) acc[qt][dt] = f32x4{0.f, 0.f, 0.f, 0.f};
    float lsum[4] = {0.f, 0.f, 0.f, 0.f};

    // V staging (pair's 128 threads): rows kva,kva+1, d in [dc, dc+16)
    const int tp = t & 127;
    const int kva = 2 * (tp & 31);
    const int dc = 16 * (tp >> 5);

    // pre-loop: K tile 0 DMA into buf0; V tile 0 into regs
    {
        bf16_t* dst = (bf16_t*)(pairBase + w * 4096);
#pragma unroll
        for (int i = 0; i < 4; i++)
            gl_lds16(((i & 1) ? kO : kE) + i * 512, dst + i * 512);
        kE += 4096; kO += 4096;
    }
    bf16x8 vr0 = ld8(Vp + (size_t)kva * HD + dc);
    bf16x8 vr1 = ld8(Vp + (size_t)(kva + 1) * HD + dc);
    bf16x8 vr2 = ld8(Vp + (size_t)kva * HD + dc + 8);
    bf16x8 vr3 = ld8(Vp + (size_t)(kva + 1) * HD + dc + 8);

    for (int kt = 0; kt < 32; kt++) {
        uint32_t* vt = (uint32_t*)(pairBase + 16384 + (kt & 1) * 8192);

        // V transpose+swizzle stage for tile kt
#pragma unroll
        for (int j = 0; j < 8; j++) {
            int d0 = dc + j;
            int sv0 = (d0 & 7) ^ ((d0 >> 3) & 7);
            vt[d0 * 32 + (((kva >> 3) ^ sv0) & 7) * 4 + ((kva & 6) >> 1)] = pack2(vr0[j], vr1[j]);
            int d1 = dc + 8 + j;
            int sv1 = (d1 & 7) ^ ((d1 >> 3) & 7);
            vt[d1 * 32 + (((kva >> 3) ^ sv1) & 7) * 4 + ((kva & 6) >> 1)] = pack2(vr2[j], vr3[j]);
        }

        __syncthreads();   // drains K-DMA(kt), V writes visible, prev readers done

        // prefetch tile kt+1: K via DMA into other buf, V into regs
        if (kt + 1 < 32) {
            bf16_t* dst = (bf16_t*)(pairBase + ((kt + 1) & 1) * 8192 + w * 4096);
#pragma unroll
            for (int i = 0; i < 4; i++)
                gl_lds16(((i & 1) ? kO : kE) + i * 512, dst + i * 512);
            kE += 4096; kO += 4096;
            int kv0n = (kt + 1) * 64;
            vr0 = ld8(Vp + (size_t)(kv0n + kva) * HD + dc);
            vr1 = ld8(Vp + (size_t)(kv0n + kva + 1) * HD + dc);
            vr2 = ld8(Vp + (size_t)(kv0n + kva) * HD + dc + 8);
            vr3 = ld8(Vp + (size_t)(kv0n + kva + 1) * HD + dc + 8);
        }

        const uint4* kl = (const uint4*)(pairBase + (kt & 1) * 8192);

        // S^T = K*Q^T, kv-permuted rows
        f32x4 st[4][4];
#pragma unroll
        for (int n = 0; n < 4; n++) {
            int kvr = (n >> 1) * 32 + ((c >> 2) * 8) + ((n & 1) * 4) + (c & 3);
            int sk = (kvr & 3) | (((kvr >> 3) & 1) << 2);
            bf16x8 k0 = *reinterpret_cast<const bf16x8*>(&kl[kvr * 8 + (quad ^ sk)]);
            bf16x8 k1 = *reinterpret_cast<const bf16x8*>(&kl[kvr * 8 + ((4 + quad) ^ sk)]);
#pragma unroll
            for (int qt = 0; qt < 4; qt++) {
                f32x4 z = f32x4{0.f, 0.f, 0.f, 0.f};
                z = mfma16(k0, qf[qt][0], z);
                z = mfma16(k1, qf[qt][1], z);
                st[qt][n] = z;
            }
        }

        // softmax without max-subtraction (exp2 domain)
        bf16x8 pf[4][2];
#pragma unroll
        for (int qt = 0; qt < 4; qt++) {
            float e[4][4];
            float ls = 0.f;
#pragma unroll
            for (int n = 0; n < 4; n++)
#pragma unroll
                for (int r = 0; r < 4; r++) {
                    float v = __builtin_amdgcn_exp2f(st[qt][n][r]);
                    e[n][r] = v;
                    ls += v;
                }
            lsum[qt] += ls;
            bf16x8 f0, f1;
#pragma unroll
            for (int j = 0; j < 8; j++) {
                f0[j] = (bf16_t)e[(j >> 2)][j & 3];
                f1[j] = (bf16_t)e[2 + (j >> 2)][j & 3];
            }
            pf[qt][0] = f0;
            pf[qt][1] = f1;
        }

        // O^T += V^T * P^T
#pragma unroll
        for (int dt = 0; dt < 4; dt++) {
            int d = dt * 16 + c;
            int sv = (d & 7) ^ ((d >> 3) & 7);
            bf16x8 v0f = *reinterpret_cast<const bf16x8*>(&vt[d * 32 + ((quad ^ sv) & 7) * 4]);
            bf16x8 v1f = *reinterpret_cast<const bf16x8*>(&vt[d * 32 + (((4 + quad) ^ sv) & 7) * 4]);
#pragma unroll
            for (int qt = 0; qt < 4; qt++) {
                acc[qt][dt] = mfma16(v0f, pf[qt][0], acc[qt][dt]);
                acc[qt][dt] = mfma16(v1f, pf[qt][1], acc[qt][dt]);
            }
        }
    }

    float lred[4];
#pragma unroll
    for (int qt = 0; qt < 4; qt++) {
        float lt = lsum[qt];
        lt += __shfl_xor(lt, 16, 64);
        lt += __shfl_xor(lt, 32, 64);
        lred[qt] = lt;
    }

    // in-block pair-combine via LDS overlay
    __syncthreads();
    float* Ox = (float*)smem;
    float* Lx = (float*)(smem + 128 * 68 * 4);

    if (pr == 1) {
#pragma unroll
        for (int qt = 0; qt < 4; qt++) {
            int ql = w * 64 + qt * 16 + c;
#pragma unroll
            for (int dt = 0; dt < 4; dt++)
                *reinterpret_cast<f32x4*>(&Ox[ql * 68 + dt * 16 + quad * 4]) = acc[qt][dt];
            if (quad == 0) Lx[ql] = lred[qt];
        }
    }
    __syncthreads();
    if (pr == 0) {
        int b_ = bh >> 3, h = bh & 7;
#pragma unroll
        for (int qt = 0; qt < 4; qt++) {
            int ql = w * 64 + qt * 16 + c;
            float inv_l = 1.0f / (lred[qt] + Lx[ql]);
            int srow = qw + qt * 16 + c;
            bf16_t* yrow = Y + (size_t)(b_ * SEQ + srow) * DMODEL + h * HD;
#pragma unroll
            for (int dt = 0; dt < 4; dt++) {
                f32x4 o4 = acc[qt][dt] + *reinterpret_cast<const f32x4*>(&Ox[ql * 68 + dt * 16 + quad * 4]);
                bf16x4 o;
#pragma unroll
                for (int r = 0; r < 4; r++) o[r] = (bf16_t)(o4[r] * inv_l);
                *reinterpret_cast<bf16x4*>(yrow + dt * 16 + quad * 4) = o;
            }
        }
    }
}

extern "C" void kernel_launch(void* const* d_in, const int* in_sizes, int n_in,
                              void* d_out, int out_size, void* d_ws, size_t ws_size,
                              hipStream_t stream) {
    (void)in_sizes; (void)n_in; (void)out_size; (void)ws_size;
    const float* x  = (const float*)d_in[0];
    const float* Wq = (const float*)d_in[1];
    const float* Wk = (const float*)d_in[2];
    const float* Wv = (const float*)d_in[3];
    const float* Wo = (const float*)d_in[4];
    const int*   Vp = (const int*)d_in[6];
    float* out = (float*)d_out;

    bf16_t* ws  = (bf16_t*)d_ws;
    bf16_t* Xb  = ws;                    // 8192*512
    bf16_t* Wc  = Xb  + 4194304;         // [Wq|Wk|Wv]
    bf16_t* Wob = Wc  + 786432;
    bf16_t* Qb  = Wob + 262144;
    bf16_t* Kb  = Qb  + 4194304;
    bf16_t* Vb  = Kb  + 4194304;
    bf16_t* Yb  = Vb  + 4194304;

    cast_all<<<5120, 256, 0, stream>>>(x, Wq, Wk, Wv, Wo, Xb, Wc, Wob);

    gemm_qkv<<<dim3(64, 12), 256, 0, stream>>>(Xb, Wc, Qb, Kb, Vb, Vp);

    flash_attn<<<dim3(32, 16), 256, 0, stream>>>(Qb, Kb, Vb, Yb);

    gemm_out<<<dim3(64, 8), 256, 0, stream>>>(Yb, Wob, out);
}

// Round 16
// 205.863 us; speedup vs baseline: 1.3092x; 1.0018x over previous
//
#include <hip/hip_runtime.h>
#include <hip/hip_bf16.h>

#define SEQ 4096
#define BSZ 2
#define NH 8
#define HD 64
#define DMODEL 512

typedef __bf16 bf16_t;
typedef __bf16 bf16x8 __attribute__((ext_vector_type(8)));
typedef __bf16 bf16x4 __attribute__((ext_vector_type(4)));
typedef float f32x4 __attribute__((ext_vector_type(4)));

__device__ __forceinline__ f32x4 mfma16(bf16x8 a, bf16x8 b, f32x4 c) {
    return __builtin_amdgcn_mfma_f32_16x16x32_bf16(a, b, c, 0, 0, 0);
}

__device__ __forceinline__ bf16x8 ld8(const bf16_t* p) {
    return *reinterpret_cast<const bf16x8*>(p);
}

__device__ __forceinline__ uint32_t pack2(bf16_t a, bf16_t b) {
    union { bf16_t h[2]; uint32_t u; } x;
    x.h[0] = a; x.h[1] = b;
    return x.u;
}

// async global->LDS DMA, 16 B/lane; data lands at lds base + lane*16
__device__ __forceinline__ void gl_lds16(const bf16_t* g, bf16_t* l) {
    __builtin_amdgcn_global_load_lds(
        (const __attribute__((address_space(1))) uint32_t*)g,
        (__attribute__((address_space(3))) uint32_t*)l,
        16, 0, 0);
}

// ---------------- fused cast fp32 -> bf16 (x + all 4 weights) ----------------
__global__ void cast_all(const float* __restrict__ x,
                         const float* __restrict__ wq, const float* __restrict__ wk,
                         const float* __restrict__ wv, const float* __restrict__ wo,
                         bf16_t* __restrict__ Xb, bf16_t* __restrict__ Wc,
                         bf16_t* __restrict__ Wob) {
    int i = blockIdx.x * blockDim.x + threadIdx.x;
    const float* src;
    bf16_t* dst;
    int j;
    if (i < 1048576) { src = x; dst = Xb; j = i; }
    else {
        int k = i - 1048576;
        int w = k >> 16;
        j = k & 65535;
        src = (w == 0) ? wq : (w == 1) ? wk : (w == 2) ? wv : wo;
        dst = (w == 3) ? Wob : Wc + w * 262144;
    }
    float4 v = reinterpret_cast<const float4*>(src)[j];
    bf16x4 o;
    o[0] = (bf16_t)v.x; o[1] = (bf16_t)v.y; o[2] = (bf16_t)v.z; o[3] = (bf16_t)v.w;
    reinterpret_cast<bf16x4*>(dst)[j] = o;
}

// ---------------- GEMM1 + fused RoPE epilogue (double-buffered staging) ----------------
// Epilogue stores as paired dwords: adjacent lanes hold adjacent d; even
// lanes store rows 0-1, odd lanes rows 2-3 (halves store count, 4B aligned).
__global__ __launch_bounds__(256) void gemm_qkv(const bf16_t* __restrict__ A,
                                                const bf16_t* __restrict__ W,
                                                bf16_t* __restrict__ Qb,
                                                bf16_t* __restrict__ Kb,
                                                bf16_t* __restrict__ Vb,
                                                const int* __restrict__ Vpar) {
    __shared__ bf16_t As[2 * 128 * 32];   // 16 KB
    __shared__ bf16_t Bs[2 * 128 * 32];   // 16 KB
    const int lane = threadIdx.x & 63;
    const int wid = threadIdx.x >> 6;
    const int c = lane & 15, quad = lane >> 4;
    const int wm = wid & 1, wn = wid >> 1;
    const int m0 = blockIdx.x * 128;
    const int n0 = blockIdx.y * 128;

    f32x4 acc[4][4];
#pragma unroll
    for (int i = 0; i < 4; i++)
#pragma unroll
        for (int j = 0; j < 4; j++) acc[i][j] = f32x4{0.f, 0.f, 0.f, 0.f};

    const int lrow = lane >> 2;
    const int lch = lane & 3;
    const bf16_t* Ag = A + (size_t)(m0 + wid * 32 + lrow) * 512 + lch * 8;
    const bf16_t* Bg = W + (size_t)(n0 + wid * 32 + lrow) * 512 + lch * 8;
    const int w0 = (wid * 32) * 32;
    const int w1 = (wid * 32 + 16) * 32;

    gl_lds16(Ag, As + w0);
    gl_lds16(Ag + 16 * 512, As + w1);
    gl_lds16(Bg, Bs + w0);
    gl_lds16(Bg + 16 * 512, Bs + w1);

    for (int it = 0; it < 16; it++) {
        __syncthreads();   // drains DMA(it); readers of buf[it-1] done

        if (it + 1 < 16) {
            int k0 = (it + 1) * 32;
            int bo = ((it + 1) & 1) * 4096;
            gl_lds16(Ag + k0, As + bo + w0);
            gl_lds16(Ag + 16 * 512 + k0, As + bo + w1);
            gl_lds16(Bg + k0, Bs + bo + w0);
            gl_lds16(Bg + 16 * 512 + k0, Bs + bo + w1);
        }

        const bf16_t* Ab = As + (it & 1) * 4096;
        const bf16_t* Bb = Bs + (it & 1) * 4096;
        bf16x8 a[4], b[4];
#pragma unroll
        for (int i = 0; i < 4; i++) a[i] = ld8(&Ab[(wm * 64 + i * 16 + c) * 32 + quad * 8]);
#pragma unroll
        for (int j = 0; j < 4; j++) b[j] = ld8(&Bb[(wn * 64 + j * 16 + c) * 32 + quad * 8]);
#pragma unroll
        for (int i = 0; i < 4; i++)
#pragma unroll
            for (int j = 0; j < 4; j++) acc[i][j] = mfma16(a[i], b[j], acc[i][j]);
    }

    const int Vv = Vpar[0];
    const float qs = 0.1803368801111204f;   // 0.125 * log2(e)
    const bool codd = (c & 1);

#pragma unroll
    for (int i = 0; i < 4; i++) {
        int mbase = m0 + wm * 64 + i * 16 + quad * 4;
#pragma unroll
        for (int j = 0; j < 4; j++) {
            int col = n0 + wn * 64 + j * 16 + c;
            int which = col >> 9;            // uniform per (wave, j)
            int h = (col >> 6) & 7;
            int d = col & 63;
            f32x4 v = acc[i][j];
            if (which < 2) {                 // rope Q / K (wave-uniform branch)
                int fidx = (d & 31) >> 1;
                float inv = exp2f((float)fidx * -0.8304820237218407f);
                bool hi = (d >= 32);
                f32x4 part;
#pragma unroll
                for (int r = 0; r < 4; r++) part[r] = __shfl_xor(v[r], 1, 64);
#pragma unroll
                for (int r = 0; r < 4; r++) {
                    int s = (mbase + r) & 4095;
                    int tq = s / Vv;
                    int vq = s - tq * Vv;
                    float ang = (float)(hi ? vq : tq) * inv;
                    float sn = __sinf(ang), cs = __cosf(ang);
                    float xe = codd ? part[r] : v[r];
                    float xo = codd ? v[r] : part[r];
                    v[r] = codd ? (xe * sn + xo * cs) : (xe * cs - xo * sn);
                }
                if (which == 0) {
#pragma unroll
                    for (int r = 0; r < 4; r++) v[r] *= qs;
                }
            }
            bf16_t* dst = (which == 0) ? Qb : ((which == 1) ? Kb : Vb);

            // paired dword stores: even lane rows 0-1, odd lane rows 2-3
            float p0 = __shfl_xor(v[0], 1, 64);
            float p1 = __shfl_xor(v[1], 1, 64);
            float p2 = __shfl_xor(v[2], 1, 64);
            float p3 = __shfl_xor(v[3], 1, 64);
            uint32_t u0 = codd ? pack2((bf16_t)p2, (bf16_t)v[2])
                               : pack2((bf16_t)v[0], (bf16_t)p0);
            uint32_t u1 = codd ? pack2((bf16_t)p3, (bf16_t)v[3])
                               : pack2((bf16_t)v[1], (bf16_t)p1);
            int dcol = d & ~1;
            int m = mbase + (codd ? 2 : 0);
            {
                int b_ = m >> 12, s = m & 4095;
                *(uint32_t*)&dst[((size_t)(b_ * NH + h) * SEQ + s) * HD + dcol] = u0;
                m++;
                b_ = m >> 12; s = m & 4095;
                *(uint32_t*)&dst[((size_t)(b_ * NH + h) * SEQ + s) * HD + dcol] = u1;
            }
        }
    }
}

// ---------------- GEMM2: 128x64 tiles, dbuf staging, grid (64,8) ----------------
__global__ __launch_bounds__(256) void gemm_out(const bf16_t* __restrict__ A,
                                                const bf16_t* __restrict__ W,
                                                float* __restrict__ out) {
    __shared__ bf16_t As[2 * 128 * 32];   // 16 KB
    __shared__ bf16_t Bs[2 * 64 * 32];    // 8 KB
    const int t = threadIdx.x;
    const int lane = t & 63;
    const int wid = t >> 6;
    const int c = lane & 15, quad = lane >> 4;
    const int m0 = blockIdx.x * 128;
    const int n0 = blockIdx.y * 64;

    f32x4 acc[2][4];
#pragma unroll
    for (int i = 0; i < 2; i++)
#pragma unroll
        for (int j = 0; j < 4; j++) acc[i][j] = f32x4{0.f, 0.f, 0.f, 0.f};

    const int lrow = lane >> 2;
    const int lch = lane & 3;
    const bf16_t* Ag = A + (size_t)(m0 + wid * 32 + lrow) * 512 + lch * 8;
    const bf16_t* Bg = W + (size_t)(n0 + wid * 16 + lrow) * 512 + lch * 8;
    const int aw0 = (wid * 32) * 32;
    const int aw1 = (wid * 32 + 16) * 32;
    const int bw = (wid * 16) * 32;

    gl_lds16(Ag, As + aw0);
    gl_lds16(Ag + 16 * 512, As + aw1);
    gl_lds16(Bg, Bs + bw);

    for (int it = 0; it < 16; it++) {
        __syncthreads();

        if (it + 1 < 16) {
            int k0 = (it + 1) * 32;
            int ao = ((it + 1) & 1) * 4096;
            int bo = ((it + 1) & 1) * 2048;
            gl_lds16(Ag + k0, As + ao + aw0);
            gl_lds16(Ag + 16 * 512 + k0, As + ao + aw1);
            gl_lds16(Bg + k0, Bs + bo + bw);
        }

        const bf16_t* Ab = As + (it & 1) * 4096;
        const bf16_t* Bb = Bs + (it & 1) * 2048;
        bf16x8 a[2], b[4];
#pragma unroll
        for (int i = 0; i < 2; i++) a[i] = ld8(&Ab[(wid * 32 + i * 16 + c) * 32 + quad * 8]);
#pragma unroll
        for (int j = 0; j < 4; j++) b[j] = ld8(&Bb[(j * 16 + c) * 32 + quad * 8]);
#pragma unroll
        for (int i = 0; i < 2; i++)
#pragma unroll
            for (int j = 0; j < 4; j++) acc[i][j] = mfma16(a[i], b[j], acc[i][j]);
    }

#pragma unroll
    for (int i = 0; i < 2; i++) {
        int mbase = m0 + wid * 32 + i * 16 + quad * 4;
#pragma unroll
        for (int j = 0; j < 4; j++) {
            int col = n0 + j * 16 + c;
#pragma unroll
            for (int r = 0; r < 4; r++)
                out[(size_t)(mbase + r) * DMODEL + col] = acc[i][j][r];
        }
    }
}

// ---------------- Flash attention (r12 core + XCD-affinity block swizzle) ----------------
// 1D grid of 512; bh = id & 15 so id mod 8 == bh mod 8: all blocks of one
// head land on one XCD (round-robin dispatch heuristic) -> each XCD's 4 MB
// L2 serves 2 heads' KV (~4 MB) instead of 16 heads'. Pure relabeling.
// Core identical to r12 (102.5 us): K via swizzled-source DMA dbuf, V reg-
// prefetch + transposed ds_write dbuf, 1 barrier/iter, exp2-domain softmax
// without max-subtraction. Reg-file-bound at 2 waves/SIMD — do NOT reorder
// compute phases (r13) or raise launch_bounds w (r5/r7).
__global__ __launch_bounds__(256, 2) void flash_attn(const bf16_t* __restrict__ Q,
                                                     const bf16_t* __restrict__ K,
                                                     const bf16_t* __restrict__ V,
                                                     bf16_t* __restrict__ Y) {
    // per pair 32768 B: K buf0 8K | K buf1 8K | V^T buf0 8K | V^T buf1 8K
    __shared__ __align__(16) unsigned char smem[65536];

    const int t = threadIdx.x;
    const int lane = t & 63;
    const int c = lane & 15, quad = lane >> 4;
    const int wid = t >> 6;            // 0..3
    const int w = wid & 1;             // q-wave id == K-stage half id
    const int pr = wid >> 1;           // kv pair 0/1
    const int bh = blockIdx.x & 15;    // XCD-affinity: id%8 == bh%8
    const int qx = blockIdx.x >> 4;
    const int qw = qx * 128 + w * 64;

    size_t base = (size_t)bh * SEQ * HD;
    const bf16_t* Qp = Q + base;
    const bf16_t* Vp = V + base + (size_t)pr * 2048 * HD;

    unsigned char* pairBase = smem + pr * 32768;

    // K DMA swizzled source pointers: wave w stages tile rows [w*32, w*32+32)
    const bf16_t* Kpb = K + base + (size_t)pr * 2048 * HD;
    int srcOff = w * 4096 + ((lane >> 3) * 128) +
                 (((lane & 7) ^ ((lane >> 3) & 3)) * 16);
    const bf16_t* kE = (const bf16_t*)((const unsigned char*)Kpb + srcOff);
    const bf16_t* kO = (const bf16_t*)((const unsigned char*)Kpb + (srcOff ^ 64));

    bf16x8 qf[4][2];
#pragma unroll
    for (int qt = 0; qt < 4; qt++)
#pragma unroll
        for (int ks = 0; ks < 2; ks++)
            qf[qt][ks] = ld8(Qp + (size_t)(qw + qt * 16 + c) * HD + ks * 32 + quad * 8);

    f32x4 acc[4][4];
#pragma unroll
    for (int qt = 0; qt < 4; qt++)
#pragma unroll
        for (int dt = 0; dt < 4; dt++) acc[qt][dt] = f32x4{0.f, 0.f, 0.f, 0.f};
    float lsum[4] = {0.f, 0.f, 0.f, 0.f};

    // V staging (pair's 128 threads): rows kva,kva+1, d in [dc, dc+16)
    const int tp = t & 127;
    const int kva = 2 * (tp & 31);
    const int dc = 16 * (tp >> 5);

    // pre-loop: K tile 0 DMA into buf0; V tile 0 into regs
    {
        bf16_t* dst = (bf16_t*)(pairBase + w * 4096);
#pragma unroll
        for (int i = 0; i < 4; i++)
            gl_lds16(((i & 1) ? kO : kE) + i * 512, dst + i * 512);
        kE += 4096; kO += 4096;
    }
    bf16x8 vr0 = ld8(Vp + (size_t)kva * HD + dc);
    bf16x8 vr1 = ld8(Vp + (size_t)(kva + 1) * HD + dc);
    bf16x8 vr2 = ld8(Vp + (size_t)kva * HD + dc + 8);
    bf16x8 vr3 = ld8(Vp + (size_t)(kva + 1) * HD + dc + 8);

    for (int kt = 0; kt < 32; kt++) {
        uint32_t* vt = (uint32_t*)(pairBase + 16384 + (kt & 1) * 8192);

        // V transpose+swizzle stage for tile kt
#pragma unroll
        for (int j = 0; j < 8; j++) {
            int d0 = dc + j;
            int sv0 = (d0 & 7) ^ ((d0 >> 3) & 7);
            vt[d0 * 32 + (((kva >> 3) ^ sv0) & 7) * 4 + ((kva & 6) >> 1)] = pack2(vr0[j], vr1[j]);
            int d1 = dc + 8 + j;
            int sv1 = (d1 & 7) ^ ((d1 >> 3) & 7);
            vt[d1 * 32 + (((kva >> 3) ^ sv1) & 7) * 4 + ((kva & 6) >> 1)] = pack2(vr2[j], vr3[j]);
        }

        __syncthreads();   // drains K-DMA(kt), V writes visible, prev readers done

        // prefetch tile kt+1: K via DMA into other buf, V into regs
        if (kt + 1 < 32) {
            bf16_t* dst = (bf16_t*)(pairBase + ((kt + 1) & 1) * 8192 + w * 4096);
#pragma unroll
            for (int i = 0; i < 4; i++)
                gl_lds16(((i & 1) ? kO : kE) + i * 512, dst + i * 512);
            kE += 4096; kO += 4096;
            int kv0n = (kt + 1) * 64;
            vr0 = ld8(Vp + (size_t)(kv0n + kva) * HD + dc);
            vr1 = ld8(Vp + (size_t)(kv0n + kva + 1) * HD + dc);
            vr2 = ld8(Vp + (size_t)(kv0n + kva) * HD + dc + 8);
            vr3 = ld8(Vp + (size_t)(kv0n + kva + 1) * HD + dc + 8);
        }

        const uint4* kl = (const uint4*)(pairBase + (kt & 1) * 8192);

        // S^T = K*Q^T, kv-permuted rows
        f32x4 st[4][4];
#pragma unroll
        for (int n = 0; n < 4; n++) {
            int kvr = (n >> 1) * 32 + ((c >> 2) * 8) + ((n & 1) * 4) + (c & 3);
            int sk = (kvr & 3) | (((kvr >> 3) & 1) << 2);
            bf16x8 k0 = *reinterpret_cast<const bf16x8*>(&kl[kvr * 8 + (quad ^ sk)]);
            bf16x8 k1 = *reinterpret_cast<const bf16x8*>(&kl[kvr * 8 + ((4 + quad) ^ sk)]);
#pragma unroll
            for (int qt = 0; qt < 4; qt++) {
                f32x4 z = f32x4{0.f, 0.f, 0.f, 0.f};
                z = mfma16(k0, qf[qt][0], z);
                z = mfma16(k1, qf[qt][1], z);
                st[qt][n] = z;
            }
        }

        // softmax without max-subtraction (exp2 domain)
        bf16x8 pf[4][2];
#pragma unroll
        for (int qt = 0; qt < 4; qt++) {
            float e[4][4];
            float ls = 0.f;
#pragma unroll
            for (int n = 0; n < 4; n++)
#pragma unroll
                for (int r = 0; r < 4; r++) {
                    float v = __builtin_amdgcn_exp2f(st[qt][n][r]);
                    e[n][r] = v;
                    ls += v;
                }
            lsum[qt] += ls;
            bf16x8 f0, f1;
#pragma unroll
            for (int j = 0; j < 8; j++) {
                f0[j] = (bf16_t)e[(j >> 2)][j & 3];
                f1[j] = (bf16_t)e[2 + (j >> 2)][j & 3];
            }
            pf[qt][0] = f0;
            pf[qt][1] = f1;
        }

        // O^T += V^T * P^T
#pragma unroll
        for (int dt = 0; dt < 4; dt++) {
            int d = dt * 16 + c;
            int sv = (d & 7) ^ ((d >> 3) & 7);
            bf16x8 v0f = *reinterpret_cast<const bf16x8*>(&vt[d * 32 + ((quad ^ sv) & 7) * 4]);
            bf16x8 v1f = *reinterpret_cast<const bf16x8*>(&vt[d * 32 + (((4 + quad) ^ sv) & 7) * 4]);
#pragma unroll
            for (int qt = 0; qt < 4; qt++) {
                acc[qt][dt] = mfma16(v0f, pf[qt][0], acc[qt][dt]);
                acc[qt][dt] = mfma16(v1f, pf[qt][1], acc[qt][dt]);
            }
        }
    }

    float lred[4];
#pragma unroll
    for (int qt = 0; qt < 4; qt++) {
        float lt = lsum[qt];
        lt += __shfl_xor(lt, 16, 64);
        lt += __shfl_xor(lt, 32, 64);
        lred[qt] = lt;
    }

    // in-block pair-combine via LDS overlay
    __syncthreads();
    float* Ox = (float*)smem;
    float* Lx = (float*)(smem + 128 * 68 * 4);

    if (pr == 1) {
#pragma unroll
        for (int qt = 0; qt < 4; qt++) {
            int ql = w * 64 + qt * 16 + c;
#pragma unroll
            for (int dt = 0; dt < 4; dt++)
                *reinterpret_cast<f32x4*>(&Ox[ql * 68 + dt * 16 + quad * 4]) = acc[qt][dt];
            if (quad == 0) Lx[ql] = lred[qt];
        }
    }
    __syncthreads();
    if (pr == 0) {
        int b_ = bh >> 3, h = bh & 7;
#pragma unroll
        for (int qt = 0; qt < 4; qt++) {
            int ql = w * 64 + qt * 16 + c;
            float inv_l = 1.0f / (lred[qt] + Lx[ql]);
            int srow = qw + qt * 16 + c;
            bf16_t* yrow = Y + (size_t)(b_ * SEQ + srow) * DMODEL + h * HD;
#pragma unroll
            for (int dt = 0; dt < 4; dt++) {
                f32x4 o4 = acc[qt][dt] + *reinterpret_cast<const f32x4*>(&Ox[ql * 68 + dt * 16 + quad * 4]);
                bf16x4 o;
#pragma unroll
                for (int r = 0; r < 4; r++) o[r] = (bf16_t)(o4[r] * inv_l);
                *reinterpret_cast<bf16x4*>(yrow + dt * 16 + quad * 4) = o;
            }
        }
    }
}

extern "C" void kernel_launch(void* const* d_in, const int* in_sizes, int n_in,
                              void* d_out, int out_size, void* d_ws, size_t ws_size,
                              hipStream_t stream) {
    (void)in_sizes; (void)n_in; (void)out_size; (void)ws_size;
    const float* x  = (const float*)d_in[0];
    const float* Wq = (const float*)d_in[1];
    const float* Wk = (const float*)d_in[2];
    const float* Wv = (const float*)d_in[3];
    const float* Wo = (const float*)d_in[4];
    const int*   Vp = (const int*)d_in[6];
    float* out = (float*)d_out;

    bf16_t* ws  = (bf16_t*)d_ws;
    bf16_t* Xb  = ws;                    // 8192*512
    bf16_t* Wc  = Xb  + 4194304;         // [Wq|Wk|Wv]
    bf16_t* Wob = Wc  + 786432;
    bf16_t* Qb  = Wob + 262144;
    bf16_t* Kb  = Qb  + 4194304;
    bf16_t* Vb  = Kb  + 4194304;
    bf16_t* Yb  = Vb  + 4194304;

    cast_all<<<5120, 256, 0, stream>>>(x, Wq, Wk, Wv, Wo, Xb, Wc, Wob);

    gemm_qkv<<<dim3(64, 12), 256, 0, stream>>>(Xb, Wc, Qb, Kb, Vb, Vp);

    flash_attn<<<512, 256, 0, stream>>>(Qb, Kb, Vb, Yb);

    gemm_out<<<dim3(64, 8), 256, 0, stream>>>(Yb, Wob, out);
}

// Round 17
// 203.810 us; speedup vs baseline: 1.3224x; 1.0101x over previous
//
#include <hip/hip_runtime.h>
#include <hip/hip_bf16.h>

#define SEQ 4096
#define BSZ 2
#define NH 8
#define HD 64
#define DMODEL 512

typedef __bf16 bf16_t;
typedef __bf16 bf16x8 __attribute__((ext_vector_type(8)));
typedef __bf16 bf16x4 __attribute__((ext_vector_type(4)));
typedef float f32x4 __attribute__((ext_vector_type(4)));

__device__ __forceinline__ f32x4 mfma16(bf16x8 a, bf16x8 b, f32x4 c) {
    return __builtin_amdgcn_mfma_f32_16x16x32_bf16(a, b, c, 0, 0, 0);
}

__device__ __forceinline__ bf16x8 ld8(const bf16_t* p) {
    return *reinterpret_cast<const bf16x8*>(p);
}

__device__ __forceinline__ uint32_t pack2(bf16_t a, bf16_t b) {
    union { bf16_t h[2]; uint32_t u; } x;
    x.h[0] = a; x.h[1] = b;
    return x.u;
}

// async global->LDS DMA, 16 B/lane; data lands at lds base + lane*16
__device__ __forceinline__ void gl_lds16(const bf16_t* g, bf16_t* l) {
    __builtin_amdgcn_global_load_lds(
        (const __attribute__((address_space(1))) uint32_t*)g,
        (__attribute__((address_space(3))) uint32_t*)l,
        16, 0, 0);
}

// ---------------- cast fp32 -> bf16, weights only ----------------
__global__ void cast_w(const float* __restrict__ wq, const float* __restrict__ wk,
                       const float* __restrict__ wv, const float* __restrict__ wo,
                       bf16_t* __restrict__ Wc, bf16_t* __restrict__ Wob) {
    int i = blockIdx.x * blockDim.x + threadIdx.x;   // 0..262143 float4 groups
    int w = i >> 16, j = i & 65535;
    const float* src = (w == 0) ? wq : (w == 1) ? wk : (w == 2) ? wv : wo;
    bf16_t* dst = (w == 3) ? Wob : Wc + w * 262144;
    float4 v = reinterpret_cast<const float4*>(src)[j];
    bf16x4 o;
    o[0] = (bf16_t)v.x; o[1] = (bf16_t)v.y; o[2] = (bf16_t)v.z; o[3] = (bf16_t)v.w;
    reinterpret_cast<bf16x4*>(dst)[j] = o;
}

// ---------------- GEMM1: fp32 A (x) + bf16 W, fused cast + RoPE epilogue ----------------
// A staged flash-V-style: float4 reg-prefetch -> cvt bf16 -> ds_write_b64 at
// loop top (before barrier); B staged via swizzle-free DMA. Dbuf, 1
// barrier/iter. Kills the separate x-cast kernel + its 16 MB round trip.
__global__ __launch_bounds__(256) void gemm_qkv(const float* __restrict__ A,
                                                const bf16_t* __restrict__ W,
                                                bf16_t* __restrict__ Qb,
                                                bf16_t* __restrict__ Kb,
                                                bf16_t* __restrict__ Vb,
                                                const int* __restrict__ Vpar) {
    __shared__ bf16_t As[2 * 128 * 32];   // 16 KB
    __shared__ bf16_t Bs[2 * 128 * 32];   // 16 KB
    const int lane = threadIdx.x & 63;
    const int wid = threadIdx.x >> 6;
    const int c = lane & 15, quad = lane >> 4;
    const int wm = wid & 1, wn = wid >> 1;
    const int m0 = blockIdx.x * 128;
    const int n0 = blockIdx.y * 128;

    f32x4 acc[4][4];
#pragma unroll
    for (int i = 0; i < 4; i++)
#pragma unroll
        for (int j = 0; j < 4; j++) acc[i][j] = f32x4{0.f, 0.f, 0.f, 0.f};

    // B staging (DMA): wave covers rows [wid*32, wid*32+32) in 2 calls
    const int lrow = lane >> 2;
    const int lch = lane & 3;
    const bf16_t* Bg = W + (size_t)(n0 + wid * 32 + lrow) * 512 + lch * 8;
    const int w0 = (wid * 32) * 32;
    const int w1 = (wid * 32 + 16) * 32;

    // A staging (regs+cvt): lane covers row wid*32 + i*8 + (lane>>3),
    // cols (lane&7)*4 .. +3 (float4), i = 0..3
    const float* Ag32 = A + (size_t)(m0 + wid * 32 + (lane >> 3)) * 512 + (lane & 7) * 4;
    bf16_t* Aw = As + (wid * 32 + (lane >> 3)) * 32 + (lane & 7) * 4;

    // pre-loop: tile 0
    float4 ar[4];
#pragma unroll
    for (int i = 0; i < 4; i++)
        ar[i] = *reinterpret_cast<const float4*>(Ag32 + (size_t)i * 8 * 512);
    gl_lds16(Bg, Bs + w0);
    gl_lds16(Bg + 16 * 512, Bs + w1);

    for (int it = 0; it < 16; it++) {
        // write A(it) regs -> LDS buf[it&1] (cvt fp32->bf16)
        bf16_t* aw = Aw + (it & 1) * 4096;
#pragma unroll
        for (int i = 0; i < 4; i++) {
            bf16x4 c4;
            c4[0] = (bf16_t)ar[i].x; c4[1] = (bf16_t)ar[i].y;
            c4[2] = (bf16_t)ar[i].z; c4[3] = (bf16_t)ar[i].w;
            *reinterpret_cast<bf16x4*>(aw + i * 8 * 32) = c4;
        }

        __syncthreads();   // drains B-DMA(it); A writes visible; prev readers done

        if (it + 1 < 16) {
            int k0 = (it + 1) * 32;
            int bo = ((it + 1) & 1) * 4096;
            gl_lds16(Bg + k0, Bs + bo + w0);
            gl_lds16(Bg + 16 * 512 + k0, Bs + bo + w1);
#pragma unroll
            for (int i = 0; i < 4; i++)
                ar[i] = *reinterpret_cast<const float4*>(Ag32 + (size_t)i * 8 * 512 + k0);
        }

        const bf16_t* Ab = As + (it & 1) * 4096;
        const bf16_t* Bb = Bs + (it & 1) * 4096;
        bf16x8 a[4], b[4];
#pragma unroll
        for (int i = 0; i < 4; i++) a[i] = ld8(&Ab[(wm * 64 + i * 16 + c) * 32 + quad * 8]);
#pragma unroll
        for (int j = 0; j < 4; j++) b[j] = ld8(&Bb[(wn * 64 + j * 16 + c) * 32 + quad * 8]);
#pragma unroll
        for (int i = 0; i < 4; i++)
#pragma unroll
            for (int j = 0; j < 4; j++) acc[i][j] = mfma16(a[i], b[j], acc[i][j]);
    }

    const int Vv = Vpar[0];
    const float qs = 0.1803368801111204f;   // 0.125 * log2(e)
    const bool codd = (c & 1);

#pragma unroll
    for (int i = 0; i < 4; i++) {
        int mbase = m0 + wm * 64 + i * 16 + quad * 4;
#pragma unroll
        for (int j = 0; j < 4; j++) {
            int col = n0 + wn * 64 + j * 16 + c;
            int which = col >> 9;            // uniform per (wave, j)
            int h = (col >> 6) & 7;
            int d = col & 63;
            f32x4 v = acc[i][j];
            if (which < 2) {                 // rope Q / K (wave-uniform branch)
                int fidx = (d & 31) >> 1;
                float inv = exp2f((float)fidx * -0.8304820237218407f);
                bool hi = (d >= 32);
                f32x4 part;
#pragma unroll
                for (int r = 0; r < 4; r++) part[r] = __shfl_xor(v[r], 1, 64);
#pragma unroll
                for (int r = 0; r < 4; r++) {
                    int s = (mbase + r) & 4095;
                    int tq = s / Vv;
                    int vq = s - tq * Vv;
                    float ang = (float)(hi ? vq : tq) * inv;
                    float sn = __sinf(ang), cs = __cosf(ang);
                    float xe = codd ? part[r] : v[r];
                    float xo = codd ? v[r] : part[r];
                    v[r] = codd ? (xe * sn + xo * cs) : (xe * cs - xo * sn);
                }
                if (which == 0) {
#pragma unroll
                    for (int r = 0; r < 4; r++) v[r] *= qs;
                }
            }
            bf16_t* dst = (which == 0) ? Qb : ((which == 1) ? Kb : Vb);

            // paired dword stores: even lane rows 0-1, odd lane rows 2-3
            float p0 = __shfl_xor(v[0], 1, 64);
            float p1 = __shfl_xor(v[1], 1, 64);
            float p2 = __shfl_xor(v[2], 1, 64);
            float p3 = __shfl_xor(v[3], 1, 64);
            uint32_t u0 = codd ? pack2((bf16_t)p2, (bf16_t)v[2])
                               : pack2((bf16_t)v[0], (bf16_t)p0);
            uint32_t u1 = codd ? pack2((bf16_t)p3, (bf16_t)v[3])
                               : pack2((bf16_t)v[1], (bf16_t)p1);
            int dcol = d & ~1;
            int m = mbase + (codd ? 2 : 0);
            {
                int b_ = m >> 12, s = m & 4095;
                *(uint32_t*)&dst[((size_t)(b_ * NH + h) * SEQ + s) * HD + dcol] = u0;
                m++;
                b_ = m >> 12; s = m & 4095;
                *(uint32_t*)&dst[((size_t)(b_ * NH + h) * SEQ + s) * HD + dcol] = u1;
            }
        }
    }
}

// ---------------- GEMM2: 128x64 tiles, dbuf staging, grid (64,8) ----------------
__global__ __launch_bounds__(256) void gemm_out(const bf16_t* __restrict__ A,
                                                const bf16_t* __restrict__ W,
                                                float* __restrict__ out) {
    __shared__ bf16_t As[2 * 128 * 32];   // 16 KB
    __shared__ bf16_t Bs[2 * 64 * 32];    // 8 KB
    const int t = threadIdx.x;
    const int lane = t & 63;
    const int wid = t >> 6;
    const int c = lane & 15, quad = lane >> 4;
    const int m0 = blockIdx.x * 128;
    const int n0 = blockIdx.y * 64;

    f32x4 acc[2][4];
#pragma unroll
    for (int i = 0; i < 2; i++)
#pragma unroll
        for (int j = 0; j < 4; j++) acc[i][j] = f32x4{0.f, 0.f, 0.f, 0.f};

    const int lrow = lane >> 2;
    const int lch = lane & 3;
    const bf16_t* Ag = A + (size_t)(m0 + wid * 32 + lrow) * 512 + lch * 8;
    const bf16_t* Bg = W + (size_t)(n0 + wid * 16 + lrow) * 512 + lch * 8;
    const int aw0 = (wid * 32) * 32;
    const int aw1 = (wid * 32 + 16) * 32;
    const int bw = (wid * 16) * 32;

    gl_lds16(Ag, As + aw0);
    gl_lds16(Ag + 16 * 512, As + aw1);
    gl_lds16(Bg, Bs + bw);

    for (int it = 0; it < 16; it++) {
        __syncthreads();

        if (it + 1 < 16) {
            int k0 = (it + 1) * 32;
            int ao = ((it + 1) & 1) * 4096;
            int bo = ((it + 1) & 1) * 2048;
            gl_lds16(Ag + k0, As + ao + aw0);
            gl_lds16(Ag + 16 * 512 + k0, As + ao + aw1);
            gl_lds16(Bg + k0, Bs + bo + bw);
        }

        const bf16_t* Ab = As + (it & 1) * 4096;
        const bf16_t* Bb = Bs + (it & 1) * 2048;
        bf16x8 a[2], b[4];
#pragma unroll
        for (int i = 0; i < 2; i++) a[i] = ld8(&Ab[(wid * 32 + i * 16 + c) * 32 + quad * 8]);
#pragma unroll
        for (int j = 0; j < 4; j++) b[j] = ld8(&Bb[(j * 16 + c) * 32 + quad * 8]);
#pragma unroll
        for (int i = 0; i < 2; i++)
#pragma unroll
            for (int j = 0; j < 4; j++) acc[i][j] = mfma16(a[i], b[j], acc[i][j]);
    }

#pragma unroll
    for (int i = 0; i < 2; i++) {
        int mbase = m0 + wid * 32 + i * 16 + quad * 4;
#pragma unroll
        for (int j = 0; j < 4; j++) {
            int col = n0 + j * 16 + c;
#pragma unroll
            for (int r = 0; r < 4; r++)
                out[(size_t)(mbase + r) * DMODEL + col] = acc[i][j][r];
        }
    }
}

// ---------------- Flash attention (r16: r12 core + XCD-affinity swizzle) ----------------
// 1D grid of 512; bh = id & 15 so id mod 8 == bh mod 8 -> one head's KV per
// XCD L2 (FETCH 71.6 -> 14.3 MB measured r16). Core = r12: K via swizzled-
// source DMA dbuf, V reg-prefetch + transposed ds_write dbuf, 1 barrier/iter,
// exp2-domain softmax without max-subtraction. Reg-file-bound at 2
// waves/SIMD — do NOT reorder compute phases (r13) or raise launch_bounds w
// (r5/r7).
__global__ __launch_bounds__(256, 2) void flash_attn(const bf16_t* __restrict__ Q,
                                                     const bf16_t* __restrict__ K,
                                                     const bf16_t* __restrict__ V,
                                                     bf16_t* __restrict__ Y) {
    // per pair 32768 B: K buf0 8K | K buf1 8K | V^T buf0 8K | V^T buf1 8K
    __shared__ __align__(16) unsigned char smem[65536];

    const int t = threadIdx.x;
    const int lane = t & 63;
    const int c = lane & 15, quad = lane >> 4;
    const int wid = t >> 6;            // 0..3
    const int w = wid & 1;             // q-wave id == K-stage half id
    const int pr = wid >> 1;           // kv pair 0/1
    const int bh = blockIdx.x & 15;    // XCD-affinity: id%8 == bh%8
    const int qx = blockIdx.x >> 4;
    const int qw = qx * 128 + w * 64;

    size_t base = (size_t)bh * SEQ * HD;
    const bf16_t* Qp = Q + base;
    const bf16_t* Vp = V + base + (size_t)pr * 2048 * HD;

    unsigned char* pairBase = smem + pr * 32768;

    // K DMA swizzled source pointers: wave w stages tile rows [w*32, w*32+32)
    const bf16_t* Kpb = K + base + (size_t)pr * 2048 * HD;
    int srcOff = w * 4096 + ((lane >> 3) * 128) +
                 (((lane & 7) ^ ((lane >> 3) & 3)) * 16);
    const bf16_t* kE = (const bf16_t*)((const unsigned char*)Kpb + srcOff);
    const bf16_t* kO = (const bf16_t*)((const unsigned char*)Kpb + (srcOff ^ 64));

    bf16x8 qf[4][2];
#pragma unroll
    for (int qt = 0; qt < 4; qt++)
#pragma unroll
        for (int ks = 0; ks < 2; ks++)
            qf[qt][ks] = ld8(Qp + (size_t)(qw + qt * 16 + c) * HD + ks * 32 + quad * 8);

    f32x4 acc[4][4];
#pragma unroll
    for (int qt = 0; qt < 4; qt++)
#pragma unroll
        for (int dt = 0; dt < 4; dt++) acc[qt][dt] = f32x4{0.f, 0.f, 0.f, 0.f};
    float lsum[4] = {0.f, 0.f, 0.f, 0.f};

    // V staging (pair's 128 threads): rows kva,kva+1, d in [dc, dc+16)
    const int tp = t & 127;
    const int kva = 2 * (tp & 31);
    const int dc = 16 * (tp >> 5);

    // pre-loop: K tile 0 DMA into buf0; V tile 0 into regs
    {
        bf16_t* dst = (bf16_t*)(pairBase + w * 4096);
#pragma unroll
        for (int i = 0; i < 4; i++)
            gl_lds16(((i & 1) ? kO : kE) + i * 512, dst + i * 512);
        kE += 4096; kO += 4096;
    }
    bf16x8 vr0 = ld8(Vp + (size_t)kva * HD + dc);
    bf16x8 vr1 = ld8(Vp + (size_t)(kva + 1) * HD + dc);
    bf16x8 vr2 = ld8(Vp + (size_t)kva * HD + dc + 8);
    bf16x8 vr3 = ld8(Vp + (size_t)(kva + 1) * HD + dc + 8);

    for (int kt = 0; kt < 32; kt++) {
        uint32_t* vt = (uint32_t*)(pairBase + 16384 + (kt & 1) * 8192);

        // V transpose+swizzle stage for tile kt
#pragma unroll
        for (int j = 0; j < 8; j++) {
            int d0 = dc + j;
            int sv0 = (d0 & 7) ^ ((d0 >> 3) & 7);
            vt[d0 * 32 + (((kva >> 3) ^ sv0) & 7) * 4 + ((kva & 6) >> 1)] = pack2(vr0[j], vr1[j]);
            int d1 = dc + 8 + j;
            int sv1 = (d1 & 7) ^ ((d1 >> 3) & 7);
            vt[d1 * 32 + (((kva >> 3) ^ sv1) & 7) * 4 + ((kva & 6) >> 1)] = pack2(vr2[j], vr3[j]);
        }

        __syncthreads();   // drains K-DMA(kt), V writes visible, prev readers done

        // prefetch tile kt+1: K via DMA into other buf, V into regs
        if (kt + 1 < 32) {
            bf16_t* dst = (bf16_t*)(pairBase + ((kt + 1) & 1) * 8192 + w * 4096);
#pragma unroll
            for (int i = 0; i < 4; i++)
                gl_lds16(((i & 1) ? kO : kE) + i * 512, dst + i * 512);
            kE += 4096; kO += 4096;
            int kv0n = (kt + 1) * 64;
            vr0 = ld8(Vp + (size_t)(kv0n + kva) * HD + dc);
            vr1 = ld8(Vp + (size_t)(kv0n + kva + 1) * HD + dc);
            vr2 = ld8(Vp + (size_t)(kv0n + kva) * HD + dc + 8);
            vr3 = ld8(Vp + (size_t)(kv0n + kva + 1) * HD + dc + 8);
        }

        const uint4* kl = (const uint4*)(pairBase + (kt & 1) * 8192);

        // S^T = K*Q^T, kv-permuted rows
        f32x4 st[4][4];
#pragma unroll
        for (int n = 0; n < 4; n++) {
            int kvr = (n >> 1) * 32 + ((c >> 2) * 8) + ((n & 1) * 4) + (c & 3);
            int sk = (kvr & 3) | (((kvr >> 3) & 1) << 2);
            bf16x8 k0 = *reinterpret_cast<const bf16x8*>(&kl[kvr * 8 + (quad ^ sk)]);
            bf16x8 k1 = *reinterpret_cast<const bf16x8*>(&kl[kvr * 8 + ((4 + quad) ^ sk)]);
#pragma unroll
            for (int qt = 0; qt < 4; qt++) {
                f32x4 z = f32x4{0.f, 0.f, 0.f, 0.f};
                z = mfma16(k0, qf[qt][0], z);
                z = mfma16(k1, qf[qt][1], z);
                st[qt][n] = z;
            }
        }

        // softmax without max-subtraction (exp2 domain)
        bf16x8 pf[4][2];
#pragma unroll
        for (int qt = 0; qt < 4; qt++) {
            float e[4][4];
            float ls = 0.f;
#pragma unroll
            for (int n = 0; n < 4; n++)
#pragma unroll
                for (int r = 0; r < 4; r++) {
                    float v = __builtin_amdgcn_exp2f(st[qt][n][r]);
                    e[n][r] = v;
                    ls += v;
                }
            lsum[qt] += ls;
            bf16x8 f0, f1;
#pragma unroll
            for (int j = 0; j < 8; j++) {
                f0[j] = (bf16_t)e[(j >> 2)][j & 3];
                f1[j] = (bf16_t)e[2 + (j >> 2)][j & 3];
            }
            pf[qt][0] = f0;
            pf[qt][1] = f1;
        }

        // O^T += V^T * P^T
#pragma unroll
        for (int dt = 0; dt < 4; dt++) {
            int d = dt * 16 + c;
            int sv = (d & 7) ^ ((d >> 3) & 7);
            bf16x8 v0f = *reinterpret_cast<const bf16x8*>(&vt[d * 32 + ((quad ^ sv) & 7) * 4]);
            bf16x8 v1f = *reinterpret_cast<const bf16x8*>(&vt[d * 32 + (((4 + quad) ^ sv) & 7) * 4]);
#pragma unroll
            for (int qt = 0; qt < 4; qt++) {
                acc[qt][dt] = mfma16(v0f, pf[qt][0], acc[qt][dt]);
                acc[qt][dt] = mfma16(v1f, pf[qt][1], acc[qt][dt]);
            }
        }
    }

    float lred[4];
#pragma unroll
    for (int qt = 0; qt < 4; qt++) {
        float lt = lsum[qt];
        lt += __shfl_xor(lt, 16, 64);
        lt += __shfl_xor(lt, 32, 64);
        lred[qt] = lt;
    }

    // in-block pair-combine via LDS overlay
    __syncthreads();
    float* Ox = (float*)smem;
    float* Lx = (float*)(smem + 128 * 68 * 4);

    if (pr == 1) {
#pragma unroll
        for (int qt = 0; qt < 4; qt++) {
            int ql = w * 64 + qt * 16 + c;
#pragma unroll
            for (int dt = 0; dt < 4; dt++)
                *reinterpret_cast<f32x4*>(&Ox[ql * 68 + dt * 16 + quad * 4]) = acc[qt][dt];
            if (quad == 0) Lx[ql] = lred[qt];
        }
    }
    __syncthreads();
    if (pr == 0) {
        int b_ = bh >> 3, h = bh & 7;
#pragma unroll
        for (int qt = 0; qt < 4; qt++) {
            int ql = w * 64 + qt * 16 + c;
            float inv_l = 1.0f / (lred[qt] + Lx[ql]);
            int srow = qw + qt * 16 + c;
            bf16_t* yrow = Y + (size_t)(b_ * SEQ + srow) * DMODEL + h * HD;
#pragma unroll
            for (int dt = 0; dt < 4; dt++) {
                f32x4 o4 = acc[qt][dt] + *reinterpret_cast<const f32x4*>(&Ox[ql * 68 + dt * 16 + quad * 4]);
                bf16x4 o;
#pragma unroll
                for (int r = 0; r < 4; r++) o[r] = (bf16_t)(o4[r] * inv_l);
                *reinterpret_cast<bf16x4*>(yrow + dt * 16 + quad * 4) = o;
            }
        }
    }
}

extern "C" void kernel_launch(void* const* d_in, const int* in_sizes, int n_in,
                              void* d_out, int out_size, void* d_ws, size_t ws_size,
                              hipStream_t stream) {
    (void)in_sizes; (void)n_in; (void)out_size; (void)ws_size;
    const float* x  = (const float*)d_in[0];
    const float* Wq = (const float*)d_in[1];
    const float* Wk = (const float*)d_in[2];
    const float* Wv = (const float*)d_in[3];
    const float* Wo = (const float*)d_in[4];
    const int*   Vp = (const int*)d_in[6];
    float* out = (float*)d_out;

    bf16_t* ws  = (bf16_t*)d_ws;
    bf16_t* Wc  = ws;                    // [Wq|Wk|Wv] 3*512*512
    bf16_t* Wob = Wc  + 786432;          // 512*512
    bf16_t* Qb  = Wob + 262144;
    bf16_t* Kb  = Qb  + 4194304;
    bf16_t* Vb  = Kb  + 4194304;
    bf16_t* Yb  = Vb  + 4194304;

    cast_w<<<1024, 256, 0, stream>>>(Wq, Wk, Wv, Wo, Wc, Wob);

    gemm_qkv<<<dim3(64, 12), 256, 0, stream>>>(x, Wc, Qb, Kb, Vb, Vp);

    flash_attn<<<512, 256, 0, stream>>>(Qb, Kb, Vb, Yb);

    gemm_out<<<dim3(64, 8), 256, 0, stream>>>(Yb, Wob, out);
}